// Round 4
// baseline (514.214 us; speedup 1.0000x reference)
//
#include <hip/hip_runtime.h>
#include <hip/hip_bf16.h>
#include <cstdint>

#define NN 50000
#define TT 128
#define INF 6
#define HH 32
#define NE 2000
#define NI 150000
#define RR 16

typedef __attribute__((ext_vector_type(4)))  float f32x4;
typedef __attribute__((ext_vector_type(16))) float f32x16;
typedef __attribute__((ext_vector_type(8)))  short short8;

__device__ __forceinline__ float lrelu(float x, float s){ return x > 0.f ? x : s*x; }

// ---- packed bf16 helpers (v_cvt_pk_bf16_f32 path) ----
__device__ __forceinline__ unsigned pk2(float a, float b){        // [bf16(a) | bf16(b)<<16]
  union { __hip_bfloat162 h; unsigned u; } t;
  t.h = __float22bfloat162_rn(make_float2(a, b));
  return t.u;
}
__device__ __forceinline__ void pkhl(float a, float b, unsigned &hi, unsigned &lo){
  hi = pk2(a, b);
  float ha = __uint_as_float(hi << 16);
  float hb = __uint_as_float(hi & 0xFFFF0000u);
  lo = pk2(a - ha, b - hb);
}
__device__ __forceinline__ unsigned pksplit(float x){             // (hi(x), lo(x)) in one u32
  unsigned h = pk2(x, 0.f) & 0xFFFFu;
  float hf = __uint_as_float(h << 16);
  unsigned l = pk2(x - hf, 0.f) & 0xFFFFu;
  return h | (l << 16);
}
__device__ __forceinline__ short8 mk8(unsigned a, unsigned b, unsigned c, unsigned d){
  union { unsigned u[4]; short8 v; } t;
  t.u[0]=a; t.u[1]=b; t.u[2]=c; t.u[3]=d;
  return t.v;
}
#define MFMA32 __builtin_amdgcn_mfma_f32_32x32x16_bf16

// =====================================================================
// GRU: R0's verified 32x32 kernel, byte-identical (233.5us x3 runs).
// R0-R3 evidence: GRU dur invariant 233-240us across tile shape, wave
// count, WG shape; VALUBusy 52-57 + Mfma 18-21 -> issue-work plateau
// (40 wave-trans/step dominates). Parked; this round attacks the
// scatter chain instead (atomic scatter -> CSR gather, zero atomics).
// =====================================================================
__global__ __launch_bounds__(64,2) void gru_mfma(
    const float* __restrict__ price,
    const float* __restrict__ W_ih, const float* __restrict__ W_hh,
    const float* __restrict__ b_ih, const float* __restrict__ b_hh,
    const float* __restrict__ W1,
    float* __restrict__ xw, float* __restrict__ eaccZ)
{
  __shared__ __align__(16) unsigned xs[2][2048];   // [buf][32 nodes * 64 u32] = 16 KB

  const int lane = threadIdx.x;
  const int a    = lane & 31;    // node col
  const int hb   = lane >> 5;    // half: 0=lo, 1=hi
  const int n0   = blockIdx.x*32;   // 1563 blocks; last block 16 valid nodes

  // harmless eacc zero (eacc rewritten by egather; kept to stay byte-identical to R0)
  { int gt = blockIdx.x*64 + lane; if (gt < NE*HH) eaccZ[gt] = 0.f; }

  // const slots P6=(1,1)bf16, P7=0 per cell, both buffers
  for (int idx = lane; idx < 512; idx += 64){
    int bsel = idx >> 8, rem = idx & 255;
    int nd = rem >> 3, t7 = rem & 7;
    int swz = (nd&7)<<2;
    xs[bsel][nd*64 + ((t7*8+6) ^ swz)] = 0x3F803F80u;
    xs[bsel][nd*64 + ((t7*8+7) ^ swz)] = 0u;
  }

  // ---- A fragments ----
  short8 AxA[3], Ahh[3][2], Ahl[3][2];   // [tile][K-chain]
#pragma unroll
  for (int T=0; T<3; T++){
    const int gr = T*32 + a;             // gate row: r=0-31, z=32-63, n=64-95
    const float sc = (T<2) ? -1.44269504f : 2.88539008f;
    // x-path A: lo lanes k0-7 = {W0..W5, W0,W1}; hi k8-15 = {W2..W5, bh,bl, 0,0}
    const float* vi = W_ih + gr*INF;
    const float w0=vi[0]*sc, w1=vi[1]*sc, w2=vi[2]*sc, w3=vi[3]*sc, w4=vi[4]*sc, w5=vi[5]*sc;
    const float bias = (b_ih[gr] + ((T<2) ? b_hh[gr] : 0.f)) * sc;
    if (hb==0) AxA[T] = mk8(pk2(w0,w1), pk2(w2,w3), pk2(w4,w5), pk2(w0,w1));
    else       AxA[T] = mk8(pk2(w2,w3), pk2(w4,w5), pksplit(bias), 0u);
    // h-path A (double-bf16 weights), chain m covers k=16m..16m+15
#pragma unroll
    for (int m=0; m<2; m++){
      const float* wp = W_hh + gr*HH + m*16 + hb*8;
      float4 wa = *(const float4*)(wp);
      float4 wb = *(const float4*)(wp+4);
      wa.x*=sc; wa.y*=sc; wa.z*=sc; wa.w*=sc;
      wb.x*=sc; wb.y*=sc; wb.z*=sc; wb.w*=sc;
      unsigned h0,l0,h1,l1,h2,l2,h3,l3;
      pkhl(wa.x,wa.y,h0,l0); pkhl(wa.z,wa.w,h1,l1);
      pkhl(wb.x,wb.y,h2,l2); pkhl(wb.z,wb.w,h3,l3);
      Ahh[T][m] = mk8(h0,h1,h2,h3);
      Ahl[T][m] = mk8(l0,l1,l2,l3);
    }
  }
  // b_hh n-rows (scaled) in the C operand of the NH tile
  f32x16 BHN;
#pragma unroll
  for (int r=0; r<16; r++){
    int row = (r&3) + 8*(r>>2) + 4*hb;
    BHN[r] = b_hh[2*HH + row] * 2.88539008f;
  }
  const f32x16 Z16 = {0.f,0.f,0.f,0.f,0.f,0.f,0.f,0.f,0.f,0.f,0.f,0.f,0.f,0.f,0.f,0.f};

  float h[16];
#pragma unroll
  for (int r=0;r<16;r++) h[r]=0.f;
  short8 Bh1 = mk8(0,0,0,0), Bh2 = mk8(0,0,0,0);

  // ---- staging: 32 nodes x 48 floats per chunk = 6 float4 per lane ----
  float4 ld[6];
#define PREFETCH(C) { \
  _Pragma("unroll") \
  for (int q=0;q<6;q++){ \
    int id=q*64+lane, a2=id/12, off=id%12; \
    int na=n0+a2; if (na>NN-1) na=NN-1; \
    ld[q] = *(const float4*)(price + (size_t)na*(TT*INF) + (C)*48 + off*4); \
  } }
#define STAGE(BUF) { \
  _Pragma("unroll") \
  for (int q=0;q<6;q++){ \
    int id=q*64+lane, a2=id/12, off=id%12; \
    int swz=(a2&7)<<2; unsigned* row=(BUF)+a2*64; \
    _Pragma("unroll") \
    for (int p=0;p<2;p++){ \
      float e0 = p? ld[q].z : ld[q].x; \
      float e1 = p? ld[q].w : ld[q].y; \
      int b = off*4 + p*2; int ttl = b/6; int ii = b - ttl*6; \
      unsigned hi_, lo_; pkhl(e0, e1, hi_, lo_); \
      row[(ttl*8 + (ii>>1)) ^ swz]     = hi_; \
      row[(ttl*8 + 3 + (ii>>1)) ^ swz] = lo_; \
    } } }

  PREFETCH(0); STAGE(&xs[0][0]);

  const int roff = (hb<<2) ^ ((a&7)<<2);

#pragma unroll 1
  for (int c=0;c<16;c++){
    if (c<15) PREFETCH(c+1);
    const unsigned* cell = &xs[c&1][a*64];
    unsigned* sb = &xs[(c&1)^1][0];
#pragma unroll 1
    for (int tt=0; tt<8; tt++){
      union{uint4 u; short8 s;} cv;
      cv.u = *(const uint4*)(cell + ((tt*8) ^ roff));
      // x-path: ONE mfma per tile (xh*Wh + xl*Wh + bias)
      f32x16 aR  = MFMA32(AxA[0], cv.s, Z16, 0,0,0);
      f32x16 aZ  = MFMA32(AxA[1], cv.s, Z16, 0,0,0);
      f32x16 aNX = MFMA32(AxA[2], cv.s, Z16, 0,0,0);
      f32x16 aNH = MFMA32(Ahh[2][0], Bh1, BHN, 0,0,0);
      // h-path: 2 terms x 2 K-chains
      aR = MFMA32(Ahh[0][0], Bh1, aR, 0,0,0); aR = MFMA32(Ahh[0][1], Bh2, aR, 0,0,0);
      aR = MFMA32(Ahl[0][0], Bh1, aR, 0,0,0); aR = MFMA32(Ahl[0][1], Bh2, aR, 0,0,0);
      aZ = MFMA32(Ahh[1][0], Bh1, aZ, 0,0,0); aZ = MFMA32(Ahh[1][1], Bh2, aZ, 0,0,0);
      aZ = MFMA32(Ahl[1][0], Bh1, aZ, 0,0,0); aZ = MFMA32(Ahl[1][1], Bh2, aZ, 0,0,0);
      aNH= MFMA32(Ahh[2][1], Bh2, aNH,0,0,0);
      aNH= MFMA32(Ahl[2][0], Bh1, aNH,0,0,0); aNH= MFMA32(Ahl[2][1], Bh2, aNH,0,0,0);
      // gates
#define GUPD(hvar, AR, AZ, ANX, ANH) { \
      float er = __builtin_amdgcn_exp2f(AR); \
      float rr = __builtin_amdgcn_rcpf(1.f + er); \
      float p  = (ANX) + rr*(ANH); \
      float ez = __builtin_amdgcn_exp2f(AZ); \
      float et = __builtin_amdgcn_exp2f(p); \
      float etp = et + 1.f, etm = et - 1.f; \
      float num = hvar*etp + ez*etm; \
      float den = (1.f + ez) * etp; \
      hvar = num * __builtin_amdgcn_rcpf(den); }
#pragma unroll
      for (int r=0;r<16;r++) GUPD(h[r], aR[r], aZ[r], aNX[r], aNH[r]);
      // D -> next-step B: pack pairs, half-exchange lane<->lane+32
      unsigned c0=pk2(h[0],h[1]),  c1=pk2(h[2],h[3]),  c2=pk2(h[4],h[5]),  c3=pk2(h[6],h[7]);
      unsigned c4=pk2(h[8],h[9]),  c5=pk2(h[10],h[11]), c6=pk2(h[12],h[13]), c7=pk2(h[14],h[15]);
      unsigned p0=__shfl_xor(c0,32,64), p1=__shfl_xor(c1,32,64);
      unsigned p2=__shfl_xor(c2,32,64), p3=__shfl_xor(c3,32,64);
      unsigned p4=__shfl_xor(c4,32,64), p5=__shfl_xor(c5,32,64);
      unsigned p6=__shfl_xor(c6,32,64), p7=__shfl_xor(c7,32,64);
      unsigned v0 = hb? p2 : c0, v1 = hb? p3 : c1, v2 = hb? c2 : p0, v3 = hb? c3 : p1;
      unsigned w0 = hb? p6 : c4, w1 = hb? p7 : c5, w2 = hb? c6 : p4, w3 = hb? c7 : p5;
      Bh1 = mk8(v0,v1,v2,v3);
      Bh2 = mk8(w0,w1,w2,w3);
    }
    if (c<15) STAGE(sb);
  }

  // ---- epilogue: lrelu(h), then xw = lrelu(h) @ W1^T (one 32x32 tile, 3-term) ----
  float* ldsF = (float*)&xs[0][0];   // reuse staging LDS; pad-33 transpose buffer
#pragma unroll
  for (int r=0;r<16;r++){
    int row = (r&3) + 8*(r>>2) + 4*hb;
    ldsF[a*33 + row] = lrelu(h[r], 0.01f);
  }
  // build B fragments of lrelu(h): lane (col=a) reads rows k = m*16 + hb*8 + e
  float b1v[8], b2v[8];
#pragma unroll
  for (int e=0;e<8;e++){
    b1v[e] = ldsF[a*33 + hb*8 + e];
    b2v[e] = ldsF[a*33 + 16 + hb*8 + e];
  }
  unsigned q0,s0,q1,s1,q2,s2,q3,s3;
  pkhl(b1v[0],b1v[1],q0,s0); pkhl(b1v[2],b1v[3],q1,s1);
  pkhl(b1v[4],b1v[5],q2,s2); pkhl(b1v[6],b1v[7],q3,s3);
  short8 Brh1 = mk8(q0,q1,q2,q3), Brl1 = mk8(s0,s1,s2,s3);
  pkhl(b2v[0],b2v[1],q0,s0); pkhl(b2v[2],b2v[3],q1,s1);
  pkhl(b2v[4],b2v[5],q2,s2); pkhl(b2v[6],b2v[7],q3,s3);
  short8 Brh2 = mk8(q0,q1,q2,q3), Brl2 = mk8(s0,s1,s2,s3);
  // W1 A fragments (feature = a), 2 K-chains, hi/lo
  short8 W1h[2], W1l[2];
#pragma unroll
  for (int m=0;m<2;m++){
    const float* wp = W1 + a*HH + m*16 + hb*8;
    float4 wa = *(const float4*)(wp);
    float4 wb = *(const float4*)(wp+4);
    unsigned h0,l0,h1,l1,h2,l2,h3,l3;
    pkhl(wa.x,wa.y,h0,l0); pkhl(wa.z,wa.w,h1,l1);
    pkhl(wb.x,wb.y,h2,l2); pkhl(wb.z,wb.w,h3,l3);
    W1h[m] = mk8(h0,h1,h2,h3);
    W1l[m] = mk8(l0,l1,l2,l3);
  }
  f32x16 o = MFMA32(W1h[0], Brh1, Z16, 0,0,0);
  o = MFMA32(W1h[1], Brh2, o, 0,0,0);
  o = MFMA32(W1h[0], Brl1, o, 0,0,0);
  o = MFMA32(W1h[1], Brl2, o, 0,0,0);
  o = MFMA32(W1l[0], Brh1, o, 0,0,0);
  o = MFMA32(W1l[1], Brh2, o, 0,0,0);
  // transpose via LDS (overwrites the rh buffer; same wave, ordered) and store coalesced
#pragma unroll
  for (int r=0;r<16;r++){
    int row = (r&3) + 8*(r>>2) + 4*hb;
    ldsF[a*33 + row] = o[r];
  }
  {
    int nn = lane>>1, f0 = (lane&1)*16;
    if (n0 + nn < NN){
#pragma unroll
      for (int q=0;q<4;q++){
        float4 v;
        v.x = ldsF[nn*33 + f0 + q*4 + 0];
        v.y = ldsF[nn*33 + f0 + q*4 + 1];
        v.z = ldsF[nn*33 + f0 + q*4 + 2];
        v.w = ldsF[nn*33 + f0 + q*4 + 3];
        *(float4*)(xw + (size_t)(n0+nn)*HH + f0 + q*4) = v;
      }
    }
  }
}

// ============== CSR build (once, reused by both convs) ==============
// d_out slack layout (ints/floats, 800000 slots total; fin_final
// overwrites [0,800000) at the very end):
//   eacc  f32[64000]  @ 0
//   eoff  i32[2001]   @ 64000
//   noff  i32[50001]  @ 66001
//   ecur  i32[2000]   @ 116002   (counts, then cursors)
//   ncur  i32[50000]  @ 118002
//   elist i32[150000] @ 168002   (node ids per edge)
//   nlist i32[150000] @ 318002   (edge ids per node)
//   end 468002 < 800000
#define O_EACC  0
#define O_EOFF  64000
#define O_NOFF  66001
#define O_ECUR  116002
#define O_NCUR  118002
#define O_ELIST 168002
#define O_NLIST 318002

__global__ __launch_bounds__(256) void csr_count(const int* __restrict__ nidx, const int* __restrict__ eidx,
                                                 int* __restrict__ ncnt, int* __restrict__ ecnt){
  int i = blockIdx.x*256 + threadIdx.x;
  if (i < NI){
    atomicAdd(&ecnt[eidx[i]], 1);
    atomicAdd(&ncnt[nidx[i]], 1);
  }
}

// single-block exclusive scan over node counts (50000) and edge counts (2000);
// writes offsets and initializes cursors (cursor array aliases the count array).
__global__ __launch_bounds__(1024) void csr_scan(int* __restrict__ ncntcur, int* __restrict__ noff,
                                                 int* __restrict__ ecntcur, int* __restrict__ eoff){
  __shared__ int lds[1024];
  int tid = threadIdx.x;
  { // nodes: N=50000, chunk 49
    const int N = NN, C = 49;
    int base = tid*C, s = 0;
    for (int k=0;k<C;k++){ int i=base+k; if (i<N) s += ncntcur[i]; }
    lds[tid] = s; __syncthreads();
    if (tid==0){ int run=0; for (int t=0;t<1024;t++){ int v=lds[t]; lds[t]=run; run+=v; } }
    __syncthreads();
    int run = lds[tid];
    for (int k=0;k<C;k++){ int i=base+k; if (i<N){ int cv=ncntcur[i]; noff[i]=run; ncntcur[i]=run; run+=cv; } }
    if (tid==0) noff[N] = NI;
    __syncthreads();
  }
  { // edges: N=2000, chunk 2
    const int N = NE, C = 2;
    int base = tid*C, s = 0;
    for (int k=0;k<C;k++){ int i=base+k; if (i<N) s += ecntcur[i]; }
    lds[tid] = s; __syncthreads();
    if (tid==0){ int run=0; for (int t=0;t<1024;t++){ int v=lds[t]; lds[t]=run; run+=v; } }
    __syncthreads();
    int run = lds[tid];
    for (int k=0;k<C;k++){ int i=base+k; if (i<N){ int cv=ecntcur[i]; eoff[i]=run; ecntcur[i]=run; run+=cv; } }
    if (tid==0) eoff[N] = NI;
  }
}

__global__ __launch_bounds__(256) void csr_fill(const int* __restrict__ nidx, const int* __restrict__ eidx,
                                                int* __restrict__ ncur, int* __restrict__ ecur,
                                                int* __restrict__ nlist, int* __restrict__ elist){
  int i = blockIdx.x*256 + threadIdx.x;
  if (i < NI){
    int nd = nidx[i], e = eidx[i];
    int se = atomicAdd(&ecur[e], 1);
    elist[se] = nd;                    // edge -> node ids
    int sn = atomicAdd(&ncur[nd], 1);
    nlist[sn] = e;                     // node -> edge ids
  }
}

// ====== conv gathers: zero atomics, plain coalesced writes ======
// one wave per edge: eacc[e] = (1/B_e) * sum_{incident nodes} xw[node]
__global__ __launch_bounds__(256) void egather(const float* __restrict__ xw, const int* __restrict__ elist,
                                               const int* __restrict__ eoff, float* __restrict__ eacc){
  int wv = blockIdx.x*4 + (threadIdx.x>>6);   // 500*4 = 2000 exact
  int lane = threadIdx.x & 63;
  int f = lane & 31, k = lane >> 5;
  int o0 = eoff[wv], o1 = eoff[wv+1];
  float acc = 0.f;
  for (int j = o0 + k; j < o1; j += 2)
    acc += xw[(size_t)elist[j]*HH + f];
  acc += __shfl_xor(acc, 32, 64);
  int d = o1 - o0;
  float bi = d > 0 ? 1.f/(float)d : 0.f;
  if (lane < 32) eacc[(size_t)wv*HH + lane] = acc*bi;
}

// one wave per node: nacc[n] = sum_{incident edges} eacc[e]; degD[n] = deg
__global__ __launch_bounds__(256) void ngather(const float* __restrict__ eacc, const int* __restrict__ nlist,
                                               const int* __restrict__ noff, float* __restrict__ nacc,
                                               float* __restrict__ degD){
  int wv = blockIdx.x*4 + (threadIdx.x>>6);   // 12500*4 = 50000 exact
  int lane = threadIdx.x & 63;
  int f = lane & 31, k = lane >> 5;
  int o0 = noff[wv], o1 = noff[wv+1];
  float acc = 0.f;
  for (int j = o0 + k; j < o1; j += 2)
    acc += eacc[(size_t)nlist[j]*HH + f];
  acc += __shfl_xor(acc, 32, 64);
  if (lane == 0) degD[wv] = (float)(o1 - o0);
  if (lane < 32) nacc[(size_t)wv*HH + lane] = acc;
}

// ---------------- x1 = leaky(nacc*Dinv + b, .2); Y = x1 @ W^T; nacc:=0; eacc:=0 ----------------
__global__ __launch_bounds__(256) void finmm(float* __restrict__ nacc, const float* __restrict__ degD,
                                             const float* __restrict__ bias, const float* __restrict__ W,
                                             float* __restrict__ Y, float* __restrict__ eacc){
  __shared__ float sWt[HH*HH];
  __shared__ float sX[8*HH];
  int tid = threadIdx.x;
  if (blockIdx.x < 250) eacc[blockIdx.x*256 + tid] = 0.f;   // harmless (egather rewrites)
  int f0 = tid>>5, k = tid&31;
#pragma unroll
  for (int q=0;q<4;q++) sWt[k*HH + (q*8+f0)] = W[(q*8+f0)*HH + k];
  size_t base = (size_t)blockIdx.x*8*HH;
  int n = blockIdx.x*8 + (tid>>5);
  float d = degD[n];
  float dinv = d > 0.f ? 1.f/d : 0.f;
  sX[tid] = lrelu(nacc[base + tid]*dinv + bias[tid&31], 0.2f);
  nacc[base + tid] = 0.f;   // harmless (ngather rewrites)
  __syncthreads();
  float a = 0.f;
#pragma unroll
  for (int kk=0;kk<HH;kk++) a += sX[(tid>>5)*HH+kk]*sWt[kk*HH+(tid&31)];
  Y[base + tid] = a;
}

// ---------------- x2 = leaky(nacc*Dinv + b2, .2); out = leaky(x2@Wl^T + bl, .01) ----------------
__global__ __launch_bounds__(256) void fin_final(const float* __restrict__ nacc, const float* __restrict__ degD,
                                                 const float* __restrict__ b2, const float* __restrict__ Wl,
                                                 const float* __restrict__ bl, float* __restrict__ out){
  __shared__ float sWl[HH*RR];
  __shared__ float sX[8*HH];
  int tid = threadIdx.x;
#pragma unroll
  for (int q=0;q<2;q++){
    int idx = q*256 + tid;        // 512 = RR*HH
    int r = idx >> 5, kk = idx & 31;
    sWl[kk*RR + r] = Wl[idx];
  }
  size_t base = (size_t)blockIdx.x*8*HH;
  int n = blockIdx.x*8 + (tid>>5);
  float d = degD[n];
  float dinv = d > 0.f ? 1.f/d : 0.f;
  sX[tid] = lrelu(nacc[base + tid]*dinv + b2[tid&31], 0.2f);
  __syncthreads();
  int ln = tid>>5, r = tid&31;
  if (r < RR){
    float a = bl[r];
#pragma unroll
    for (int kk=0;kk<HH;kk++) a += sX[ln*HH+kk]*sWl[kk*RR+r];
    out[(size_t)(blockIdx.x*8+ln)*RR + r] = lrelu(a, 0.01f);
  }
}

extern "C" void kernel_launch(void* const* d_in, const int* in_sizes, int n_in,
                              void* d_out, int out_size, void* d_ws, size_t ws_size,
                              hipStream_t stream){
  const float* price = (const float*)d_in[0];
  // d_in[1] = concept: unused (PreAttn path disabled in reference)
  const float* W_ih = (const float*)d_in[2];
  const float* W_hh = (const float*)d_in[3];
  const float* b_ih = (const float*)d_in[4];
  const float* b_hh = (const float*)d_in[5];
  const float* W1   = (const float*)d_in[6];
  const float* b1   = (const float*)d_in[7];
  const float* W2   = (const float*)d_in[8];
  const float* b2   = (const float*)d_in[9];
  const float* Wl   = (const float*)d_in[10];
  const float* bl   = (const float*)d_in[11];
  const int* nidx   = (const int*)d_in[12];
  const int* eidx   = (const int*)d_in[13];
  float* out = (float*)d_out;
  int*  outI = (int*)d_out;

  // ws layout: xw | nacc | degD (degB slot unused now)
  float* ws   = (float*)d_ws;
  float* xw   = ws;                 // N*32
  float* nacc = ws + 1600000;       // N*32
  float* degD = ws + 3200000;       // 50000

  // d_out slack (dead until fin_final overwrites everything)
  float* eacc = out  + O_EACC;
  int* eoff   = outI + O_EOFF;
  int* noff   = outI + O_NOFF;
  int* ecur   = outI + O_ECUR;
  int* ncur   = outI + O_NCUR;
  int* elist  = outI + O_ELIST;
  int* nlist  = outI + O_NLIST;

  // zero the count/cursor arrays (contiguous 52000 ints); only memset needed now
  hipMemsetAsync(ecur, 0, (O_ELIST - O_ECUR)*sizeof(int), stream);

  // CSR build (independent of GRU output)
  csr_count<<<586, 256, 0, stream>>>(nidx, eidx, ncur, ecur);
  csr_scan<<<1, 1024, 0, stream>>>(ncur, noff, ecur, eoff);
  csr_fill<<<586, 256, 0, stream>>>(nidx, eidx, ncur, ecur, nlist, elist);

  gru_mfma<<<1563, 64, 0, stream>>>(price, W_ih, W_hh, b_ih, b_hh, W1, xw, eacc);

  // conv1: gather-only (zero atomics)
  egather<<<500,  256, 0, stream>>>(xw, elist, eoff, eacc);
  ngather<<<12500,256, 0, stream>>>(eacc, nlist, noff, nacc, degD);
  finmm<<<6250, 256, 0, stream>>>(nacc, degD, b1, W2, xw, eacc);   // x1 -> @W2 -> xw

  // conv2
  egather<<<500,  256, 0, stream>>>(xw, elist, eoff, eacc);
  ngather<<<12500,256, 0, stream>>>(eacc, nlist, noff, nacc, degD);
  fin_final<<<6250, 256, 0, stream>>>(nacc, degD, b2, Wl, bl, out);
}

// Round 5
// 445.276 us; speedup vs baseline: 1.1548x; 1.1548x over previous
//
#include <hip/hip_runtime.h>
#include <hip/hip_bf16.h>
#include <cstdint>

#define NN 50000
#define TT 128
#define INF 6
#define HH 32
#define NE 2000
#define NI 150000
#define RR 16

typedef __attribute__((ext_vector_type(4)))  float f32x4;
typedef __attribute__((ext_vector_type(16))) float f32x16;
typedef __attribute__((ext_vector_type(8)))  short short8;

__device__ __forceinline__ float lrelu(float x, float s){ return x > 0.f ? x : s*x; }

// ---- packed bf16 helpers (v_cvt_pk_bf16_f32 path) ----
__device__ __forceinline__ unsigned pk2(float a, float b){        // [bf16(a) | bf16(b)<<16]
  union { __hip_bfloat162 h; unsigned u; } t;
  t.h = __float22bfloat162_rn(make_float2(a, b));
  return t.u;
}
__device__ __forceinline__ void pkhl(float a, float b, unsigned &hi, unsigned &lo){
  hi = pk2(a, b);
  float ha = __uint_as_float(hi << 16);
  float hb = __uint_as_float(hi & 0xFFFF0000u);
  lo = pk2(a - ha, b - hb);
}
__device__ __forceinline__ unsigned pksplit(float x){             // (hi(x), lo(x)) in one u32
  unsigned h = pk2(x, 0.f) & 0xFFFFu;
  float hf = __uint_as_float(h << 16);
  unsigned l = pk2(x - hf, 0.f) & 0xFFFFu;
  return h | (l << 16);
}
__device__ __forceinline__ short8 mk8(unsigned a, unsigned b, unsigned c, unsigned d){
  union { unsigned u[4]; short8 v; } t;
  t.u[0]=a; t.u[1]=b; t.u[2]=c; t.u[3]=d;
  return t.v;
}
#define MFMA32 __builtin_amdgcn_mfma_f32_32x32x16_bf16

// =====================================================================
// GRU: R0's verified 32x32 kernel, byte-identical (233.5us x3 runs).
// Parked at its issue-work plateau (R0-R3 evidence). This round fixes
// the CSR path: R4's csr_scan had a serial 2x1024-iteration thread-0
// LDS loop (~120cyc dependent ds ops ~ 110-150us) -> parallel scan;
// egather gets 8 MLP streams; finmm/fin_final fused into the node
// gathers (removes two 6.4MB array round-trips and 2 dispatches).
// =====================================================================
__global__ __launch_bounds__(64,2) void gru_mfma(
    const float* __restrict__ price,
    const float* __restrict__ W_ih, const float* __restrict__ W_hh,
    const float* __restrict__ b_ih, const float* __restrict__ b_hh,
    const float* __restrict__ W1,
    float* __restrict__ xw, float* __restrict__ eaccZ)
{
  __shared__ __align__(16) unsigned xs[2][2048];   // [buf][32 nodes * 64 u32] = 16 KB

  const int lane = threadIdx.x;
  const int a    = lane & 31;    // node col
  const int hb   = lane >> 5;    // half: 0=lo, 1=hi
  const int n0   = blockIdx.x*32;   // 1563 blocks; last block 16 valid nodes

  // harmless eacc zero (eacc rewritten by egather; kept to stay byte-identical)
  { int gt = blockIdx.x*64 + lane; if (gt < NE*HH) eaccZ[gt] = 0.f; }

  // const slots P6=(1,1)bf16, P7=0 per cell, both buffers
  for (int idx = lane; idx < 512; idx += 64){
    int bsel = idx >> 8, rem = idx & 255;
    int nd = rem >> 3, t7 = rem & 7;
    int swz = (nd&7)<<2;
    xs[bsel][nd*64 + ((t7*8+6) ^ swz)] = 0x3F803F80u;
    xs[bsel][nd*64 + ((t7*8+7) ^ swz)] = 0u;
  }

  // ---- A fragments ----
  short8 AxA[3], Ahh[3][2], Ahl[3][2];   // [tile][K-chain]
#pragma unroll
  for (int T=0; T<3; T++){
    const int gr = T*32 + a;             // gate row: r=0-31, z=32-63, n=64-95
    const float sc = (T<2) ? -1.44269504f : 2.88539008f;
    // x-path A: lo lanes k0-7 = {W0..W5, W0,W1}; hi k8-15 = {W2..W5, bh,bl, 0,0}
    const float* vi = W_ih + gr*INF;
    const float w0=vi[0]*sc, w1=vi[1]*sc, w2=vi[2]*sc, w3=vi[3]*sc, w4=vi[4]*sc, w5=vi[5]*sc;
    const float bias = (b_ih[gr] + ((T<2) ? b_hh[gr] : 0.f)) * sc;
    if (hb==0) AxA[T] = mk8(pk2(w0,w1), pk2(w2,w3), pk2(w4,w5), pk2(w0,w1));
    else       AxA[T] = mk8(pk2(w2,w3), pk2(w4,w5), pksplit(bias), 0u);
    // h-path A (double-bf16 weights), chain m covers k=16m..16m+15
#pragma unroll
    for (int m=0; m<2; m++){
      const float* wp = W_hh + gr*HH + m*16 + hb*8;
      float4 wa = *(const float4*)(wp);
      float4 wb = *(const float4*)(wp+4);
      wa.x*=sc; wa.y*=sc; wa.z*=sc; wa.w*=sc;
      wb.x*=sc; wb.y*=sc; wb.z*=sc; wb.w*=sc;
      unsigned h0,l0,h1,l1,h2,l2,h3,l3;
      pkhl(wa.x,wa.y,h0,l0); pkhl(wa.z,wa.w,h1,l1);
      pkhl(wb.x,wb.y,h2,l2); pkhl(wb.z,wb.w,h3,l3);
      Ahh[T][m] = mk8(h0,h1,h2,h3);
      Ahl[T][m] = mk8(l0,l1,l2,l3);
    }
  }
  // b_hh n-rows (scaled) in the C operand of the NH tile
  f32x16 BHN;
#pragma unroll
  for (int r=0; r<16; r++){
    int row = (r&3) + 8*(r>>2) + 4*hb;
    BHN[r] = b_hh[2*HH + row] * 2.88539008f;
  }
  const f32x16 Z16 = {0.f,0.f,0.f,0.f,0.f,0.f,0.f,0.f,0.f,0.f,0.f,0.f,0.f,0.f,0.f,0.f};

  float h[16];
#pragma unroll
  for (int r=0;r<16;r++) h[r]=0.f;
  short8 Bh1 = mk8(0,0,0,0), Bh2 = mk8(0,0,0,0);

  // ---- staging: 32 nodes x 48 floats per chunk = 6 float4 per lane ----
  float4 ld[6];
#define PREFETCH(C) { \
  _Pragma("unroll") \
  for (int q=0;q<6;q++){ \
    int id=q*64+lane, a2=id/12, off=id%12; \
    int na=n0+a2; if (na>NN-1) na=NN-1; \
    ld[q] = *(const float4*)(price + (size_t)na*(TT*INF) + (C)*48 + off*4); \
  } }
#define STAGE(BUF) { \
  _Pragma("unroll") \
  for (int q=0;q<6;q++){ \
    int id=q*64+lane, a2=id/12, off=id%12; \
    int swz=(a2&7)<<2; unsigned* row=(BUF)+a2*64; \
    _Pragma("unroll") \
    for (int p=0;p<2;p++){ \
      float e0 = p? ld[q].z : ld[q].x; \
      float e1 = p? ld[q].w : ld[q].y; \
      int b = off*4 + p*2; int ttl = b/6; int ii = b - ttl*6; \
      unsigned hi_, lo_; pkhl(e0, e1, hi_, lo_); \
      row[(ttl*8 + (ii>>1)) ^ swz]     = hi_; \
      row[(ttl*8 + 3 + (ii>>1)) ^ swz] = lo_; \
    } } }

  PREFETCH(0); STAGE(&xs[0][0]);

  const int roff = (hb<<2) ^ ((a&7)<<2);

#pragma unroll 1
  for (int c=0;c<16;c++){
    if (c<15) PREFETCH(c+1);
    const unsigned* cell = &xs[c&1][a*64];
    unsigned* sb = &xs[(c&1)^1][0];
#pragma unroll 1
    for (int tt=0; tt<8; tt++){
      union{uint4 u; short8 s;} cv;
      cv.u = *(const uint4*)(cell + ((tt*8) ^ roff));
      // x-path: ONE mfma per tile (xh*Wh + xl*Wh + bias)
      f32x16 aR  = MFMA32(AxA[0], cv.s, Z16, 0,0,0);
      f32x16 aZ  = MFMA32(AxA[1], cv.s, Z16, 0,0,0);
      f32x16 aNX = MFMA32(AxA[2], cv.s, Z16, 0,0,0);
      f32x16 aNH = MFMA32(Ahh[2][0], Bh1, BHN, 0,0,0);
      // h-path: 2 terms x 2 K-chains
      aR = MFMA32(Ahh[0][0], Bh1, aR, 0,0,0); aR = MFMA32(Ahh[0][1], Bh2, aR, 0,0,0);
      aR = MFMA32(Ahl[0][0], Bh1, aR, 0,0,0); aR = MFMA32(Ahl[0][1], Bh2, aR, 0,0,0);
      aZ = MFMA32(Ahh[1][0], Bh1, aZ, 0,0,0); aZ = MFMA32(Ahh[1][1], Bh2, aZ, 0,0,0);
      aZ = MFMA32(Ahl[1][0], Bh1, aZ, 0,0,0); aZ = MFMA32(Ahl[1][1], Bh2, aZ, 0,0,0);
      aNH= MFMA32(Ahh[2][1], Bh2, aNH,0,0,0);
      aNH= MFMA32(Ahl[2][0], Bh1, aNH,0,0,0); aNH= MFMA32(Ahl[2][1], Bh2, aNH,0,0,0);
      // gates
#define GUPD(hvar, AR, AZ, ANX, ANH) { \
      float er = __builtin_amdgcn_exp2f(AR); \
      float rr = __builtin_amdgcn_rcpf(1.f + er); \
      float p  = (ANX) + rr*(ANH); \
      float ez = __builtin_amdgcn_exp2f(AZ); \
      float et = __builtin_amdgcn_exp2f(p); \
      float etp = et + 1.f, etm = et - 1.f; \
      float num = hvar*etp + ez*etm; \
      float den = (1.f + ez) * etp; \
      hvar = num * __builtin_amdgcn_rcpf(den); }
#pragma unroll
      for (int r=0;r<16;r++) GUPD(h[r], aR[r], aZ[r], aNX[r], aNH[r]);
      // D -> next-step B: pack pairs, half-exchange lane<->lane+32
      unsigned c0=pk2(h[0],h[1]),  c1=pk2(h[2],h[3]),  c2=pk2(h[4],h[5]),  c3=pk2(h[6],h[7]);
      unsigned c4=pk2(h[8],h[9]),  c5=pk2(h[10],h[11]), c6=pk2(h[12],h[13]), c7=pk2(h[14],h[15]);
      unsigned p0=__shfl_xor(c0,32,64), p1=__shfl_xor(c1,32,64);
      unsigned p2=__shfl_xor(c2,32,64), p3=__shfl_xor(c3,32,64);
      unsigned p4=__shfl_xor(c4,32,64), p5=__shfl_xor(c5,32,64);
      unsigned p6=__shfl_xor(c6,32,64), p7=__shfl_xor(c7,32,64);
      unsigned v0 = hb? p2 : c0, v1 = hb? p3 : c1, v2 = hb? c2 : p0, v3 = hb? c3 : p1;
      unsigned w0 = hb? p6 : c4, w1 = hb? p7 : c5, w2 = hb? c6 : p4, w3 = hb? c7 : p5;
      Bh1 = mk8(v0,v1,v2,v3);
      Bh2 = mk8(w0,w1,w2,w3);
    }
    if (c<15) STAGE(sb);
  }

  // ---- epilogue: lrelu(h), then xw = lrelu(h) @ W1^T (one 32x32 tile, 3-term) ----
  float* ldsF = (float*)&xs[0][0];   // reuse staging LDS; pad-33 transpose buffer
#pragma unroll
  for (int r=0;r<16;r++){
    int row = (r&3) + 8*(r>>2) + 4*hb;
    ldsF[a*33 + row] = lrelu(h[r], 0.01f);
  }
  // build B fragments of lrelu(h): lane (col=a) reads rows k = m*16 + hb*8 + e
  float b1v[8], b2v[8];
#pragma unroll
  for (int e=0;e<8;e++){
    b1v[e] = ldsF[a*33 + hb*8 + e];
    b2v[e] = ldsF[a*33 + 16 + hb*8 + e];
  }
  unsigned q0,s0,q1,s1,q2,s2,q3,s3;
  pkhl(b1v[0],b1v[1],q0,s0); pkhl(b1v[2],b1v[3],q1,s1);
  pkhl(b1v[4],b1v[5],q2,s2); pkhl(b1v[6],b1v[7],q3,s3);
  short8 Brh1 = mk8(q0,q1,q2,q3), Brl1 = mk8(s0,s1,s2,s3);
  pkhl(b2v[0],b2v[1],q0,s0); pkhl(b2v[2],b2v[3],q1,s1);
  pkhl(b2v[4],b2v[5],q2,s2); pkhl(b2v[6],b2v[7],q3,s3);
  short8 Brh2 = mk8(q0,q1,q2,q3), Brl2 = mk8(s0,s1,s2,s3);
  // W1 A fragments (feature = a), 2 K-chains, hi/lo
  short8 W1h[2], W1l[2];
#pragma unroll
  for (int m=0;m<2;m++){
    const float* wp = W1 + a*HH + m*16 + hb*8;
    float4 wa = *(const float4*)(wp);
    float4 wb = *(const float4*)(wp+4);
    unsigned h0,l0,h1,l1,h2,l2,h3,l3;
    pkhl(wa.x,wa.y,h0,l0); pkhl(wa.z,wa.w,h1,l1);
    pkhl(wb.x,wb.y,h2,l2); pkhl(wb.z,wb.w,h3,l3);
    W1h[m] = mk8(h0,h1,h2,h3);
    W1l[m] = mk8(l0,l1,l2,l3);
  }
  f32x16 o = MFMA32(W1h[0], Brh1, Z16, 0,0,0);
  o = MFMA32(W1h[1], Brh2, o, 0,0,0);
  o = MFMA32(W1h[0], Brl1, o, 0,0,0);
  o = MFMA32(W1h[1], Brl2, o, 0,0,0);
  o = MFMA32(W1l[0], Brh1, o, 0,0,0);
  o = MFMA32(W1l[1], Brh2, o, 0,0,0);
  // transpose via LDS (overwrites the rh buffer; same wave, ordered) and store coalesced
#pragma unroll
  for (int r=0;r<16;r++){
    int row = (r&3) + 8*(r>>2) + 4*hb;
    ldsF[a*33 + row] = o[r];
  }
  {
    int nn = lane>>1, f0 = (lane&1)*16;
    if (n0 + nn < NN){
#pragma unroll
      for (int q=0;q<4;q++){
        float4 v;
        v.x = ldsF[nn*33 + f0 + q*4 + 0];
        v.y = ldsF[nn*33 + f0 + q*4 + 1];
        v.z = ldsF[nn*33 + f0 + q*4 + 2];
        v.w = ldsF[nn*33 + f0 + q*4 + 3];
        *(float4*)(xw + (size_t)(n0+nn)*HH + f0 + q*4) = v;
      }
    }
  }
}

// ============== CSR build (once, reused by both convs) ==============
__global__ __launch_bounds__(256) void csr_count(const int* __restrict__ nidx, const int* __restrict__ eidx,
                                                 int* __restrict__ ncnt, int* __restrict__ ecnt){
  int i = blockIdx.x*256 + threadIdx.x;
  if (i < NI){
    atomicAdd(&ecnt[eidx[i]], 1);
    atomicAdd(&ncnt[nidx[i]], 1);
  }
}

// single-block PARALLEL exclusive scan (R5 fix: R4's serial thread-0
// 1024-iter LDS loop was ~120cyc/dep-op ~ >100us; now wave shfl scan +
// 16-entry serial wave-total pass).
__global__ __launch_bounds__(1024) void csr_scan(int* __restrict__ ncntcur, int* __restrict__ noff,
                                                 int* __restrict__ ecntcur, int* __restrict__ eoff){
  __shared__ int wsum[16];
  const int tid  = threadIdx.x;
  const int lane = tid & 63, wv = tid >> 6;
#define SCAN_SEC(CNT, OFF, N, C, TOT) { \
    int base = tid*(C); \
    int s = 0; \
    _Pragma("unroll") \
    for (int k2=0;k2<(C);k2++){ int i=base+k2; if (i<(N)) s += (CNT)[i]; } \
    int inc = s; \
    _Pragma("unroll") \
    for (int off=1; off<64; off<<=1){ int v=__shfl_up(inc,off,64); if (lane>=off) inc+=v; } \
    if (lane==63) wsum[wv] = inc; \
    __syncthreads(); \
    if (tid==0){ int run=0; \
      _Pragma("unroll") \
      for (int t=0;t<16;t++){ int v=wsum[t]; wsum[t]=run; run+=v; } } \
    __syncthreads(); \
    int run = wsum[wv] + inc - s; \
    _Pragma("unroll") \
    for (int k2=0;k2<(C);k2++){ int i=base+k2; if (i<(N)){ int cv=(CNT)[i]; (OFF)[i]=run; (CNT)[i]=run; run+=cv; } } \
    if (tid==0) (OFF)[N]=(TOT); \
    __syncthreads(); \
  }
  SCAN_SEC(ncntcur, noff, NN, 49, NI)
  SCAN_SEC(ecntcur, eoff, NE, 2, NI)
#undef SCAN_SEC
}

__global__ __launch_bounds__(256) void csr_fill(const int* __restrict__ nidx, const int* __restrict__ eidx,
                                                int* __restrict__ ncur, int* __restrict__ ecur,
                                                int* __restrict__ nlist, int* __restrict__ elist){
  int i = blockIdx.x*256 + threadIdx.x;
  if (i < NI){
    int nd = nidx[i], e = eidx[i];
    int se = atomicAdd(&ecur[e], 1);
    elist[se] = nd;                    // edge -> node ids
    int sn = atomicAdd(&ncur[nd], 1);
    nlist[sn] = e;                     // node -> edge ids
  }
}

// ====== conv gathers: zero atomics ======
// one 256-thread BLOCK per edge (8 j-streams of 32 feat-lanes -> 8x MLP):
// eacc[e] = (1/B_e) * sum_{incident nodes} xw[node]
__global__ __launch_bounds__(256) void egather(const float* __restrict__ xw, const int* __restrict__ elist,
                                               const int* __restrict__ eoff, float* __restrict__ eacc){
  __shared__ float red[8][HH];
  int e = blockIdx.x;
  int tid = threadIdx.x;
  int f = tid & 31, grp = tid >> 5;          // 8 groups
  int o0 = eoff[e], o1 = eoff[e+1];
  float acc = 0.f;
  for (int j = o0 + grp; j < o1; j += 8)
    acc += xw[(size_t)elist[j]*HH + f];
  red[grp][f] = acc;
  __syncthreads();
  if (tid < 32){
    float s = red[0][f]+red[1][f]+red[2][f]+red[3][f]
            + red[4][f]+red[5][f]+red[6][f]+red[7][f];
    int d = o1 - o0;
    float bi = d > 0 ? 1.f/(float)d : 0.f;
    eacc[(size_t)e*HH + f] = s*bi;
  }
}

// fused conv1 tail: per node (wave) gather edge means -> x1 = lrelu(acc*Dinv+b1, .2)
// -> Y = x1 @ W2^T  (replaces ngather + finmm; no nacc/degD arrays)
__global__ __launch_bounds__(256) void ngather_mm(const float* __restrict__ eacc, const int* __restrict__ nlist,
                                                  const int* __restrict__ noff, const float* __restrict__ bias,
                                                  const float* __restrict__ W, float* __restrict__ Y){
  __shared__ float sWt[HH*HH];   // sWt[k*HH+o] = W[o*HH+k]
  __shared__ float sx[4][HH];
  int tid = threadIdx.x;
  {
    int o = tid & 31, kq = tid >> 5;
#pragma unroll
    for (int q=0;q<4;q++){ int k = kq*4+q; sWt[k*HH+o] = W[o*HH+k]; }
  }
  int wv = tid >> 6, lane = tid & 63;
  int n = blockIdx.x*4 + wv;
  int f = lane & 31, k = lane >> 5;
  int o0 = noff[n], o1 = noff[n+1];
  float acc = 0.f;
  for (int j = o0 + k; j < o1; j += 2)
    acc += eacc[(size_t)nlist[j]*HH + f];
  acc += __shfl_xor(acc, 32, 64);
  int d = o1 - o0;
  float dinv = d > 0 ? 1.f/(float)d : 0.f;
  if (lane < 32) sx[wv][f] = lrelu(acc*dinv + bias[f], 0.2f);
  __syncthreads();
  if (tid < 128){
    int ln = tid >> 5, o = tid & 31;
    float a = 0.f;
#pragma unroll
    for (int kk=0;kk<HH;kk++) a += sx[ln][kk]*sWt[kk*HH+o];
    Y[(size_t)(blockIdx.x*4+ln)*HH + o] = a;
  }
}

// fused conv2 tail: gather -> x2 = lrelu(acc*Dinv+b2, .2) -> out = lrelu(x2@Wl^T+bl, .01)
__global__ __launch_bounds__(256) void ngather_fin(const float* __restrict__ eacc, const int* __restrict__ nlist,
                                                   const int* __restrict__ noff, const float* __restrict__ b2,
                                                   const float* __restrict__ Wl, const float* __restrict__ bl,
                                                   float* __restrict__ out){
  __shared__ float sWl[HH*RR];   // sWl[k*RR+r] = Wl[r*HH+k]
  __shared__ float sx[4][HH];
  __shared__ float sbl[RR];
  int tid = threadIdx.x;
#pragma unroll
  for (int q=0;q<2;q++){
    int idx = q*256 + tid;        // 512 = RR*HH
    int r = idx >> 5, kk = idx & 31;
    sWl[kk*RR + r] = Wl[idx];
  }
  if (tid < RR) sbl[tid] = bl[tid];
  int wv = tid >> 6, lane = tid & 63;
  int n = blockIdx.x*4 + wv;
  int f = lane & 31, k = lane >> 5;
  int o0 = noff[n], o1 = noff[n+1];
  float acc = 0.f;
  for (int j = o0 + k; j < o1; j += 2)
    acc += eacc[(size_t)nlist[j]*HH + f];
  acc += __shfl_xor(acc, 32, 64);
  int d = o1 - o0;
  float dinv = d > 0 ? 1.f/(float)d : 0.f;
  if (lane < 32) sx[wv][f] = lrelu(acc*dinv + b2[f], 0.2f);
  __syncthreads();
  if (tid < 64){
    int ln = tid >> 4, r = tid & 15;
    float a = sbl[r];
#pragma unroll
    for (int kk=0;kk<HH;kk++) a += sx[ln][kk]*sWl[kk*RR+r];
    out[(size_t)(blockIdx.x*4+ln)*RR + r] = lrelu(a, 0.01f);
  }
}

// ws float-offsets (proven ws = 3,252,000 floats):
//   xw    f32[1600000] @ 0
//   eacc  f32[64000]   @ 1600000
//   eoff  i32[2001]    @ 1664000
//   noff  i32[50001]   @ 1666001
//   ecur  i32[2000]    @ 1716002   (counts, then cursors; contiguous with ncur)
//   ncur  i32[50000]   @ 1718002
//   elist i32[150000]  @ 1768002
//   nlist i32[150000]  @ 1918002
//   end 2068002 < 3252000
#define X_EACC  1600000
#define X_EOFF  1664000
#define X_NOFF  1666001
#define X_ECUR  1716002
#define X_NCUR  1718002
#define X_ELIST 1768002
#define X_NLIST 1918002

extern "C" void kernel_launch(void* const* d_in, const int* in_sizes, int n_in,
                              void* d_out, int out_size, void* d_ws, size_t ws_size,
                              hipStream_t stream){
  const float* price = (const float*)d_in[0];
  // d_in[1] = concept: unused (PreAttn path disabled in reference)
  const float* W_ih = (const float*)d_in[2];
  const float* W_hh = (const float*)d_in[3];
  const float* b_ih = (const float*)d_in[4];
  const float* b_hh = (const float*)d_in[5];
  const float* W1   = (const float*)d_in[6];
  const float* b1   = (const float*)d_in[7];
  const float* W2   = (const float*)d_in[8];
  const float* b2   = (const float*)d_in[9];
  const float* Wl   = (const float*)d_in[10];
  const float* bl   = (const float*)d_in[11];
  const int* nidx   = (const int*)d_in[12];
  const int* eidx   = (const int*)d_in[13];
  float* out = (float*)d_out;

  float* ws  = (float*)d_ws;
  int*   wsI = (int*)d_ws;
  float* xw   = ws;
  float* eacc = ws  + X_EACC;
  int* eoff   = wsI + X_EOFF;
  int* noff   = wsI + X_NOFF;
  int* ecur   = wsI + X_ECUR;
  int* ncur   = wsI + X_NCUR;
  int* elist  = wsI + X_ELIST;
  int* nlist  = wsI + X_NLIST;

  // zero only the count/cursor arrays (contiguous 52000 ints)
  hipMemsetAsync(ecur, 0, (X_ELIST - X_ECUR)*sizeof(int), stream);

  // CSR build (reused by both convs)
  csr_count<<<586, 256, 0, stream>>>(nidx, eidx, ncur, ecur);
  csr_scan<<<1, 1024, 0, stream>>>(ncur, noff, ecur, eoff);
  csr_fill<<<586, 256, 0, stream>>>(nidx, eidx, ncur, ecur, nlist, elist);

  gru_mfma<<<1563, 64, 0, stream>>>(price, W_ih, W_hh, b_ih, b_hh, W1, xw, eacc);

  // conv1: gather-only; node tail fused with x1@W2^T
  egather<<<NE, 256, 0, stream>>>(xw, elist, eoff, eacc);
  ngather_mm<<<12500, 256, 0, stream>>>(eacc, nlist, noff, b1, W2, xw);

  // conv2: node tail fused with final projection
  egather<<<NE, 256, 0, stream>>>(xw, elist, eoff, eacc);
  ngather_fin<<<12500, 256, 0, stream>>>(eacc, nlist, noff, b2, Wl, bl, out);
}

// Round 6
// 401.890 us; speedup vs baseline: 1.2795x; 1.1080x over previous
//
#include <hip/hip_runtime.h>
#include <hip/hip_bf16.h>
#include <cstdint>

#define NN 50000
#define TT 128
#define INF 6
#define HH 32
#define NE 2000
#define NI 150000
#define RR 16

typedef __attribute__((ext_vector_type(4)))  float f32x4;
typedef __attribute__((ext_vector_type(16))) float f32x16;
typedef __attribute__((ext_vector_type(8)))  short short8;

__device__ __forceinline__ float lrelu(float x, float s){ return x > 0.f ? x : s*x; }

// ---- packed bf16 helpers (v_cvt_pk_bf16_f32 path) ----
__device__ __forceinline__ unsigned pk2(float a, float b){        // [bf16(a) | bf16(b)<<16]
  union { __hip_bfloat162 h; unsigned u; } t;
  t.h = __float22bfloat162_rn(make_float2(a, b));
  return t.u;
}
__device__ __forceinline__ void pkhl(float a, float b, unsigned &hi, unsigned &lo){
  hi = pk2(a, b);
  float ha = __uint_as_float(hi << 16);
  float hb = __uint_as_float(hi & 0xFFFF0000u);
  lo = pk2(a - ha, b - hb);
}
__device__ __forceinline__ unsigned pksplit(float x){             // (hi(x), lo(x)) in one u32
  unsigned h = pk2(x, 0.f) & 0xFFFFu;
  float hf = __uint_as_float(h << 16);
  unsigned l = pk2(x - hf, 0.f) & 0xFFFFu;
  return h | (l << 16);
}
__device__ __forceinline__ short8 mk8(unsigned a, unsigned b, unsigned c, unsigned d){
  union { unsigned u[4]; short8 v; } t;
  t.u[0]=a; t.u[1]=b; t.u[2]=c; t.u[3]=d;
  return t.v;
}
#define MFMA32 __builtin_amdgcn_mfma_f32_32x32x16_bf16

// =====================================================================
// GRU on mfma_f32_32x32x16_bf16 -- R6: TWO independent 32-node tiles
// per wave (64 nodes/block, 782 single-wave blocks).
// Evidence R0-R5: GRU pinned 233-240us across occupancy 12.6-20% ->
// NOT residency-limited; each wave ~50% dependency-stall (MFMA chain
// -> GUPD -> pack serial), and co-phase waves don't fill it. Tile B's
// MFMAs are independent of tile A's GUPD -> intra-wave ILP fills the
// stalls. Weights/BHN shared between tiles. launch_bounds(64,1):
// 512-VGPR ceiling so the scheduler can hold both tiles' accumulators
// (~320 VGPR expected) with ZERO spill (falsifier: WRITE_SIZE >> 6.5MB).
// Conv chain: reverted to R0's proven atomic scatter (114us; CSR
// gather measured 212us in R4/R5 -- net loss at deg_node~3).
// =====================================================================
__global__ __launch_bounds__(64,1) void gru_mfma(
    const float* __restrict__ price,
    const float* __restrict__ W_ih, const float* __restrict__ W_hh,
    const float* __restrict__ b_ih, const float* __restrict__ b_hh,
    const float* __restrict__ W1,
    float* __restrict__ xw, float* __restrict__ eaccZ)
{
  __shared__ __align__(16) unsigned xs[2][2][2048];   // [tile][buf][32 nodes * 64 u32] = 32 KB

  const int lane = threadIdx.x;
  const int a    = lane & 31;    // node col
  const int hb   = lane >> 5;    // half: 0=lo, 1=hi
  const int n0A  = blockIdx.x*64;        // tile A nodes
  const int n0B  = n0A + 32;             // tile B nodes

  // fold eacc zeroing into this launch (grid-stride: 782*64 = 50048 < 64000)
  for (int gt = blockIdx.x*64 + lane; gt < NE*HH; gt += 782*64) eaccZ[gt] = 0.f;

  // const slots P6=(1,1)bf16, P7=0 per cell, both tiles, both buffers
  for (int idx = lane; idx < 1024; idx += 64){
    int t = idx >> 9, bsel = (idx >> 8) & 1, rem = idx & 255;
    int nd = rem >> 3, t7 = rem & 7;
    int swz = (nd&7)<<2;
    xs[t][bsel][nd*64 + ((t7*8+6) ^ swz)] = 0x3F803F80u;
    xs[t][bsel][nd*64 + ((t7*8+7) ^ swz)] = 0u;
  }

  // ---- A fragments (shared by both tiles) ----
  short8 AxA[3], Ahh[3][2], Ahl[3][2];   // [gate-tile][K-chain]
#pragma unroll
  for (int T=0; T<3; T++){
    const int gr = T*32 + a;             // gate row: r=0-31, z=32-63, n=64-95
    const float sc = (T<2) ? -1.44269504f : 2.88539008f;
    const float* vi = W_ih + gr*INF;
    const float w0=vi[0]*sc, w1=vi[1]*sc, w2=vi[2]*sc, w3=vi[3]*sc, w4=vi[4]*sc, w5=vi[5]*sc;
    const float bias = (b_ih[gr] + ((T<2) ? b_hh[gr] : 0.f)) * sc;
    if (hb==0) AxA[T] = mk8(pk2(w0,w1), pk2(w2,w3), pk2(w4,w5), pk2(w0,w1));
    else       AxA[T] = mk8(pk2(w2,w3), pk2(w4,w5), pksplit(bias), 0u);
#pragma unroll
    for (int m=0; m<2; m++){
      const float* wp = W_hh + gr*HH + m*16 + hb*8;
      float4 wa = *(const float4*)(wp);
      float4 wb = *(const float4*)(wp+4);
      wa.x*=sc; wa.y*=sc; wa.z*=sc; wa.w*=sc;
      wb.x*=sc; wb.y*=sc; wb.z*=sc; wb.w*=sc;
      unsigned h0,l0,h1,l1,h2,l2,h3,l3;
      pkhl(wa.x,wa.y,h0,l0); pkhl(wa.z,wa.w,h1,l1);
      pkhl(wb.x,wb.y,h2,l2); pkhl(wb.z,wb.w,h3,l3);
      Ahh[T][m] = mk8(h0,h1,h2,h3);
      Ahl[T][m] = mk8(l0,l1,l2,l3);
    }
  }
  // b_hh n-rows (scaled) in the C operand of the NH tile
  f32x16 BHN;
#pragma unroll
  for (int r=0; r<16; r++){
    int row = (r&3) + 8*(r>>2) + 4*hb;
    BHN[r] = b_hh[2*HH + row] * 2.88539008f;
  }
  const f32x16 Z16 = {0.f,0.f,0.f,0.f,0.f,0.f,0.f,0.f,0.f,0.f,0.f,0.f,0.f,0.f,0.f,0.f};

  float hA[16], hB[16];
#pragma unroll
  for (int r=0;r<16;r++){ hA[r]=0.f; hB[r]=0.f; }
  short8 Bh1A = mk8(0,0,0,0), Bh2A = mk8(0,0,0,0);
  short8 Bh1B = mk8(0,0,0,0), Bh2B = mk8(0,0,0,0);

  // ---- staging: 32 nodes x 48 floats per chunk = 6 float4 per lane per tile ----
  float4 ldA[6], ldB[6];
#define PREFETCH(LD, N0, C) { \
  _Pragma("unroll") \
  for (int q=0;q<6;q++){ \
    int id=q*64+lane, a2=id/12, off=id%12; \
    int na=(N0)+a2; if (na>NN-1) na=NN-1; \
    LD[q] = *(const float4*)(price + (size_t)na*(TT*INF) + (C)*48 + off*4); \
  } }
#define STAGE(LD, BUF) { \
  _Pragma("unroll") \
  for (int q=0;q<6;q++){ \
    int id=q*64+lane, a2=id/12, off=id%12; \
    int swz=(a2&7)<<2; unsigned* row=(BUF)+a2*64; \
    _Pragma("unroll") \
    for (int p=0;p<2;p++){ \
      float e0 = p? LD[q].z : LD[q].x; \
      float e1 = p? LD[q].w : LD[q].y; \
      int b = off*4 + p*2; int ttl = b/6; int ii = b - ttl*6; \
      unsigned hi_, lo_; pkhl(e0, e1, hi_, lo_); \
      row[(ttl*8 + (ii>>1)) ^ swz]     = hi_; \
      row[(ttl*8 + 3 + (ii>>1)) ^ swz] = lo_; \
    } } }

#define GUPD(hvar, AR, AZ, ANX, ANH) { \
      float er = __builtin_amdgcn_exp2f(AR); \
      float rr = __builtin_amdgcn_rcpf(1.f + er); \
      float p  = (ANX) + rr*(ANH); \
      float ez = __builtin_amdgcn_exp2f(AZ); \
      float et = __builtin_amdgcn_exp2f(p); \
      float etp = et + 1.f, etm = et - 1.f; \
      float num = hvar*etp + ez*etm; \
      float den = (1.f + ez) * etp; \
      hvar = num * __builtin_amdgcn_rcpf(den); }

// MFMA chain for one tile (15 mfma): results in AR/AZ/ANX/ANH
#define MCHAIN(CV, B1, B2, AR, AZ, ANX, ANH) { \
      AR  = MFMA32(AxA[0], CV, Z16, 0,0,0); \
      AZ  = MFMA32(AxA[1], CV, Z16, 0,0,0); \
      ANX = MFMA32(AxA[2], CV, Z16, 0,0,0); \
      ANH = MFMA32(Ahh[2][0], B1, BHN, 0,0,0); \
      AR = MFMA32(Ahh[0][0], B1, AR, 0,0,0); AR = MFMA32(Ahh[0][1], B2, AR, 0,0,0); \
      AR = MFMA32(Ahl[0][0], B1, AR, 0,0,0); AR = MFMA32(Ahl[0][1], B2, AR, 0,0,0); \
      AZ = MFMA32(Ahh[1][0], B1, AZ, 0,0,0); AZ = MFMA32(Ahh[1][1], B2, AZ, 0,0,0); \
      AZ = MFMA32(Ahl[1][0], B1, AZ, 0,0,0); AZ = MFMA32(Ahl[1][1], B2, AZ, 0,0,0); \
      ANH= MFMA32(Ahh[2][1], B2, ANH,0,0,0); \
      ANH= MFMA32(Ahl[2][0], B1, ANH,0,0,0); ANH= MFMA32(Ahl[2][1], B2, ANH,0,0,0); }

// D -> next-step B operand: pack pairs, half-exchange lane<->lane+32
#define PACKB(H, B1, B2) { \
      unsigned c0=pk2(H[0],H[1]),  c1=pk2(H[2],H[3]),  c2=pk2(H[4],H[5]),  c3=pk2(H[6],H[7]); \
      unsigned c4=pk2(H[8],H[9]),  c5=pk2(H[10],H[11]), c6=pk2(H[12],H[13]), c7=pk2(H[14],H[15]); \
      unsigned p0=__shfl_xor(c0,32,64), p1=__shfl_xor(c1,32,64); \
      unsigned p2=__shfl_xor(c2,32,64), p3=__shfl_xor(c3,32,64); \
      unsigned p4=__shfl_xor(c4,32,64), p5=__shfl_xor(c5,32,64); \
      unsigned p6=__shfl_xor(c6,32,64), p7=__shfl_xor(c7,32,64); \
      unsigned v0 = hb? p2 : c0, v1 = hb? p3 : c1, v2 = hb? c2 : p0, v3 = hb? c3 : p1; \
      unsigned w0 = hb? p6 : c4, w1 = hb? p7 : c5, w2 = hb? c6 : p4, w3 = hb? c7 : p5; \
      B1 = mk8(v0,v1,v2,v3); \
      B2 = mk8(w0,w1,w2,w3); }

  PREFETCH(ldA, n0A, 0); PREFETCH(ldB, n0B, 0);
  STAGE(ldA, &xs[0][0][0]); STAGE(ldB, &xs[1][0][0]);

  const int roff = (hb<<2) ^ ((a&7)<<2);

#pragma unroll 1
  for (int c=0;c<16;c++){
    if (c<15){ PREFETCH(ldA, n0A, c+1); PREFETCH(ldB, n0B, c+1); }
    const unsigned* cellA = &xs[0][c&1][a*64];
    const unsigned* cellB = &xs[1][c&1][a*64];
    unsigned* sbA = &xs[0][(c&1)^1][0];
    unsigned* sbB = &xs[1][(c&1)^1][0];
#pragma unroll 1
    for (int tt=0; tt<8; tt++){
      union{uint4 u; short8 s;} cvA, cvB;
      cvA.u = *(const uint4*)(cellA + ((tt*8) ^ roff));
      cvB.u = *(const uint4*)(cellB + ((tt*8) ^ roff));
      f32x16 aR, aZ, aNX, aNH, bR, bZ, bNX, bNH;
      MCHAIN(cvA.s, Bh1A, Bh2A, aR, aZ, aNX, aNH);
      MCHAIN(cvB.s, Bh1B, Bh2B, bR, bZ, bNX, bNH);
      // tile A gates + pack (overlaps tile B's MFMA latency)
#pragma unroll
      for (int r=0;r<16;r++) GUPD(hA[r], aR[r], aZ[r], aNX[r], aNH[r]);
      PACKB(hA, Bh1A, Bh2A);
      // tile B gates + pack
#pragma unroll
      for (int r=0;r<16;r++) GUPD(hB[r], bR[r], bZ[r], bNX[r], bNH[r]);
      PACKB(hB, Bh1B, Bh2B);
    }
    if (c<15){ STAGE(ldA, sbA); STAGE(ldB, sbB); }
  }

  // ---- epilogue: lrelu(h), then xw = lrelu(h) @ W1^T (one 32x32 tile each, 3-term) ----
  // W1 A fragments (feature = a), 2 K-chains, hi/lo -- shared by both tiles
  short8 W1h[2], W1l[2];
#pragma unroll
  for (int m=0;m<2;m++){
    const float* wp = W1 + a*HH + m*16 + hb*8;
    float4 wa = *(const float4*)(wp);
    float4 wb = *(const float4*)(wp+4);
    unsigned h0,l0,h1,l1,h2,l2,h3,l3;
    pkhl(wa.x,wa.y,h0,l0); pkhl(wa.z,wa.w,h1,l1);
    pkhl(wb.x,wb.y,h2,l2); pkhl(wb.z,wb.w,h3,l3);
    W1h[m] = mk8(h0,h1,h2,h3);
    W1l[m] = mk8(l0,l1,l2,l3);
  }

#define EPILOG(H, LDSF, N0) { \
  _Pragma("unroll") \
  for (int r=0;r<16;r++){ \
    int row = (r&3) + 8*(r>>2) + 4*hb; \
    (LDSF)[a*33 + row] = lrelu(H[r], 0.01f); \
  } \
  float b1v[8], b2v[8]; \
  _Pragma("unroll") \
  for (int e=0;e<8;e++){ \
    b1v[e] = (LDSF)[a*33 + hb*8 + e]; \
    b2v[e] = (LDSF)[a*33 + 16 + hb*8 + e]; \
  } \
  unsigned q0,s0,q1,s1,q2,s2,q3,s3; \
  pkhl(b1v[0],b1v[1],q0,s0); pkhl(b1v[2],b1v[3],q1,s1); \
  pkhl(b1v[4],b1v[5],q2,s2); pkhl(b1v[6],b1v[7],q3,s3); \
  short8 Brh1 = mk8(q0,q1,q2,q3), Brl1 = mk8(s0,s1,s2,s3); \
  pkhl(b2v[0],b2v[1],q0,s0); pkhl(b2v[2],b2v[3],q1,s1); \
  pkhl(b2v[4],b2v[5],q2,s2); pkhl(b2v[6],b2v[7],q3,s3); \
  short8 Brh2 = mk8(q0,q1,q2,q3), Brl2 = mk8(s0,s1,s2,s3); \
  f32x16 o = MFMA32(W1h[0], Brh1, Z16, 0,0,0); \
  o = MFMA32(W1h[1], Brh2, o, 0,0,0); \
  o = MFMA32(W1h[0], Brl1, o, 0,0,0); \
  o = MFMA32(W1h[1], Brl2, o, 0,0,0); \
  o = MFMA32(W1l[0], Brh1, o, 0,0,0); \
  o = MFMA32(W1l[1], Brh2, o, 0,0,0); \
  _Pragma("unroll") \
  for (int r=0;r<16;r++){ \
    int row = (r&3) + 8*(r>>2) + 4*hb; \
    (LDSF)[a*33 + row] = o[r]; \
  } \
  { \
    int nn = lane>>1, f0 = (lane&1)*16; \
    if ((N0) + nn < NN){ \
      _Pragma("unroll") \
      for (int q=0;q<4;q++){ \
        float4 v; \
        v.x = (LDSF)[nn*33 + f0 + q*4 + 0]; \
        v.y = (LDSF)[nn*33 + f0 + q*4 + 1]; \
        v.z = (LDSF)[nn*33 + f0 + q*4 + 2]; \
        v.w = (LDSF)[nn*33 + f0 + q*4 + 3]; \
        *(float4*)(xw + (size_t)((N0)+nn)*HH + f0 + q*4) = v; \
      } \
    } \
  } }

  float* ldsFA = (float*)&xs[0][0][0];
  float* ldsFB = (float*)&xs[1][0][0];
  EPILOG(hA, ldsFA, n0A);
  EPILOG(hB, ldsFB, n0B);
}

// ---------------- scatter xw -> edge accumulators (+degree count on 1st pass) ----------------
template<bool COUNT>
__global__ __launch_bounds__(256) void scat_e(const float* __restrict__ xw, const int* __restrict__ nidx,
                                              const int* __restrict__ eidx, float* __restrict__ eacc,
                                              float* __restrict__ degD, float* __restrict__ degB){
  int idx = blockIdx.x*256 + threadIdx.x;   // NI*32 exact
  int i = idx >> 5, f = idx & 31;
  int nd = nidx[i], e = eidx[i];
  if (COUNT && f == 0){
    atomicAdd(&degD[nd], 1.f);
    atomicAdd(&degB[e], 1.f);
  }
  atomicAdd(&eacc[(size_t)e*HH + f], xw[(size_t)nd*HH + f]);
}
template __global__ void scat_e<true>(const float*, const int*, const int*, float*, float*, float*);
template __global__ void scat_e<false>(const float*, const int*, const int*, float*, float*, float*);

// ---------------- gather edge means -> node accumulators ----------------
__global__ __launch_bounds__(256) void scat_n(const float* __restrict__ eacc, const float* __restrict__ degB,
                                              const int* __restrict__ nidx, const int* __restrict__ eidx,
                                              float* __restrict__ nacc){
  int idx = blockIdx.x*256 + threadIdx.x;   // NI*32 exact
  int i = idx >> 5, f = idx & 31;
  int nd = nidx[i], e = eidx[i];
  float b = degB[e];
  float binv = b > 0.f ? 1.f/b : 0.f;
  atomicAdd(&nacc[(size_t)nd*HH + f], eacc[(size_t)e*HH + f]*binv);
}

// ---------------- x1 = leaky(nacc*Dinv + b, .2); Y = x1 @ W^T; nacc:=0; eacc:=0 ----------------
__global__ __launch_bounds__(256) void finmm(float* __restrict__ nacc, const float* __restrict__ degD,
                                             const float* __restrict__ bias, const float* __restrict__ W,
                                             float* __restrict__ Y, float* __restrict__ eacc){
  __shared__ float sWt[HH*HH];
  __shared__ float sX[8*HH];
  int tid = threadIdx.x;
  if (blockIdx.x < 250) eacc[blockIdx.x*256 + tid] = 0.f;   // re-zero for conv2 (250*256 = 64000)
  int f0 = tid>>5, k = tid&31;
#pragma unroll
  for (int q=0;q<4;q++) sWt[k*HH + (q*8+f0)] = W[(q*8+f0)*HH + k];
  size_t base = (size_t)blockIdx.x*8*HH;
  int n = blockIdx.x*8 + (tid>>5);
  float d = degD[n];
  float dinv = d > 0.f ? 1.f/d : 0.f;
  sX[tid] = lrelu(nacc[base + tid]*dinv + bias[tid&31], 0.2f);
  nacc[base + tid] = 0.f;   // reset for conv2
  __syncthreads();
  float a = 0.f;
#pragma unroll
  for (int kk=0;kk<HH;kk++) a += sX[(tid>>5)*HH+kk]*sWt[kk*HH+(tid&31)];
  Y[base + tid] = a;
}

// ---------------- x2 = leaky(nacc*Dinv + b2, .2); out = leaky(x2@Wl^T + bl, .01) ----------------
__global__ __launch_bounds__(256) void fin_final(const float* __restrict__ nacc, const float* __restrict__ degD,
                                                 const float* __restrict__ b2, const float* __restrict__ Wl,
                                                 const float* __restrict__ bl, float* __restrict__ out){
  __shared__ float sWl[HH*RR];
  __shared__ float sX[8*HH];
  int tid = threadIdx.x;
#pragma unroll
  for (int q=0;q<2;q++){
    int idx = q*256 + tid;        // 512 = RR*HH
    int r = idx >> 5, kk = idx & 31;
    sWl[kk*RR + r] = Wl[idx];
  }
  size_t base = (size_t)blockIdx.x*8*HH;
  int n = blockIdx.x*8 + (tid>>5);
  float d = degD[n];
  float dinv = d > 0.f ? 1.f/d : 0.f;
  sX[tid] = lrelu(nacc[base + tid]*dinv + b2[tid&31], 0.2f);
  __syncthreads();
  int ln = tid>>5, r = tid&31;
  if (r < RR){
    float a = bl[r];
#pragma unroll
    for (int kk=0;kk<HH;kk++) a += sX[ln*HH+kk]*sWl[kk*RR+r];
    out[(size_t)(blockIdx.x*8+ln)*RR + r] = lrelu(a, 0.01f);
  }
}

extern "C" void kernel_launch(void* const* d_in, const int* in_sizes, int n_in,
                              void* d_out, int out_size, void* d_ws, size_t ws_size,
                              hipStream_t stream){
  const float* price = (const float*)d_in[0];
  // d_in[1] = concept: unused (PreAttn path disabled in reference)
  const float* W_ih = (const float*)d_in[2];
  const float* W_hh = (const float*)d_in[3];
  const float* b_ih = (const float*)d_in[4];
  const float* b_hh = (const float*)d_in[5];
  const float* W1   = (const float*)d_in[6];
  const float* b1   = (const float*)d_in[7];
  const float* W2   = (const float*)d_in[8];
  const float* b2   = (const float*)d_in[9];
  const float* Wl   = (const float*)d_in[10];
  const float* bl   = (const float*)d_in[11];
  const int* nidx   = (const int*)d_in[12];
  const int* eidx   = (const int*)d_in[13];
  float* out = (float*)d_out;

  // ws layout (proven size): xw | nacc | degD | degB
  float* ws   = (float*)d_ws;
  float* xw   = ws;                 // N*32
  float* nacc = ws + 1600000;       // N*32
  float* degD = ws + 3200000;       // 50000
  float* degB = ws + 3250000;       // 2000
  float* eacc = out;                // NE*32 = 64000 floats in d_out; dead before fin_final

  // one memset: nacc+degD+degB contiguous. eacc zeroed inside gru_mfma.
  hipMemsetAsync(nacc, 0, (1600000+52000)*sizeof(float), stream);

  gru_mfma<<<782, 64, 0, stream>>>(price, W_ih, W_hh, b_ih, b_hh, W1, xw, eacc);

  // conv1 (xw = lrelu(hT)@W1^T fused in GRU epilogue; degrees counted in scat_e)
  scat_e<true><<<18750, 256, 0, stream>>>(xw, nidx, eidx, eacc, degD, degB);
  scat_n<<<18750, 256, 0, stream>>>(eacc, degB, nidx, eidx, nacc);
  finmm<<<6250, 256, 0, stream>>>(nacc, degD, b1, W2, xw, eacc);   // x1 -> @W2 -> xw; nacc,eacc := 0

  // conv2
  scat_e<false><<<18750, 256, 0, stream>>>(xw, nidx, eidx, eacc, degD, degB);
  scat_n<<<18750, 256, 0, stream>>>(eacc, degB, nidx, eidx, nacc);
  fin_final<<<6250, 256, 0, stream>>>(nacc, degD, b2, Wl, bl, out);
}

// Round 7
// 353.715 us; speedup vs baseline: 1.4538x; 1.1362x over previous
//
#include <hip/hip_runtime.h>
#include <hip/hip_bf16.h>
#include <cstdint>

#define NN 50000
#define TT 128
#define INF 6
#define HH 32
#define NE 2000
#define NI 150000
#define RR 16

typedef __attribute__((ext_vector_type(4)))  float f32x4;
typedef __attribute__((ext_vector_type(16))) float f32x16;
typedef __attribute__((ext_vector_type(8)))  short short8;

__device__ __forceinline__ float lrelu(float x, float s){ return x > 0.f ? x : s*x; }

// ---- packed bf16 helpers (v_cvt_pk_bf16_f32 path) ----
__device__ __forceinline__ unsigned pk2(float a, float b){        // [bf16(a) | bf16(b)<<16]
  union { __hip_bfloat162 h; unsigned u; } t;
  t.h = __float22bfloat162_rn(make_float2(a, b));
  return t.u;
}
__device__ __forceinline__ void pkhl(float a, float b, unsigned &hi, unsigned &lo){
  hi = pk2(a, b);
  float ha = __uint_as_float(hi << 16);
  float hb = __uint_as_float(hi & 0xFFFF0000u);
  lo = pk2(a - ha, b - hb);
}
__device__ __forceinline__ unsigned pksplit(float x){             // (hi(x), lo(x)) in one u32
  unsigned h = pk2(x, 0.f) & 0xFFFFu;
  float hf = __uint_as_float(h << 16);
  unsigned l = pk2(x - hf, 0.f) & 0xFFFFu;
  return h | (l << 16);
}
__device__ __forceinline__ short8 mk8(unsigned a, unsigned b, unsigned c, unsigned d){
  union { unsigned u[4]; short8 v; } t;
  t.u[0]=a; t.u[1]=b; t.u[2]=c; t.u[3]=d;
  return t.v;
}
#define MFMA32 __builtin_amdgcn_mfma_f32_32x32x16_bf16

// =====================================================================
// GRU: R0's verified 32x32 kernel, byte-identical (233.5us, 3+ runs).
// Parked (R0-R6: more waves neutral, fatter waves worse, tighter regs
// spill). R7 = controlled conv split: edge side only -> CSR+egather
// (scat_e was ~30us each of atomic-issue cost on 4096 hot lines);
// node side keeps proven atomic scat_n (low contention, 100k lines).
// =====================================================================
__global__ __launch_bounds__(64,2) void gru_mfma(
    const float* __restrict__ price,
    const float* __restrict__ W_ih, const float* __restrict__ W_hh,
    const float* __restrict__ b_ih, const float* __restrict__ b_hh,
    const float* __restrict__ W1,
    float* __restrict__ xw, float* __restrict__ eaccZ)
{
  __shared__ __align__(16) unsigned xs[2][2048];   // [buf][32 nodes * 64 u32] = 16 KB

  const int lane = threadIdx.x;
  const int a    = lane & 31;    // node col
  const int hb   = lane >> 5;    // half: 0=lo, 1=hi
  const int n0   = blockIdx.x*32;   // 1563 blocks; last block 16 valid nodes

  // harmless eacc zero (egather overwrites; kept for code-identity with R0)
  { int gt = blockIdx.x*64 + lane; if (gt < NE*HH) eaccZ[gt] = 0.f; }

  // const slots P6=(1,1)bf16, P7=0 per cell, both buffers
  for (int idx = lane; idx < 512; idx += 64){
    int bsel = idx >> 8, rem = idx & 255;
    int nd = rem >> 3, t7 = rem & 7;
    int swz = (nd&7)<<2;
    xs[bsel][nd*64 + ((t7*8+6) ^ swz)] = 0x3F803F80u;
    xs[bsel][nd*64 + ((t7*8+7) ^ swz)] = 0u;
  }

  // ---- A fragments ----
  short8 AxA[3], Ahh[3][2], Ahl[3][2];   // [tile][K-chain]
#pragma unroll
  for (int T=0; T<3; T++){
    const int gr = T*32 + a;             // gate row: r=0-31, z=32-63, n=64-95
    const float sc = (T<2) ? -1.44269504f : 2.88539008f;
    // x-path A: lo lanes k0-7 = {W0..W5, W0,W1}; hi k8-15 = {W2..W5, bh,bl, 0,0}
    const float* vi = W_ih + gr*INF;
    const float w0=vi[0]*sc, w1=vi[1]*sc, w2=vi[2]*sc, w3=vi[3]*sc, w4=vi[4]*sc, w5=vi[5]*sc;
    const float bias = (b_ih[gr] + ((T<2) ? b_hh[gr] : 0.f)) * sc;
    if (hb==0) AxA[T] = mk8(pk2(w0,w1), pk2(w2,w3), pk2(w4,w5), pk2(w0,w1));
    else       AxA[T] = mk8(pk2(w2,w3), pk2(w4,w5), pksplit(bias), 0u);
    // h-path A (double-bf16 weights), chain m covers k=16m..16m+15
#pragma unroll
    for (int m=0; m<2; m++){
      const float* wp = W_hh + gr*HH + m*16 + hb*8;
      float4 wa = *(const float4*)(wp);
      float4 wb = *(const float4*)(wp+4);
      wa.x*=sc; wa.y*=sc; wa.z*=sc; wa.w*=sc;
      wb.x*=sc; wb.y*=sc; wb.z*=sc; wb.w*=sc;
      unsigned h0,l0,h1,l1,h2,l2,h3,l3;
      pkhl(wa.x,wa.y,h0,l0); pkhl(wa.z,wa.w,h1,l1);
      pkhl(wb.x,wb.y,h2,l2); pkhl(wb.z,wb.w,h3,l3);
      Ahh[T][m] = mk8(h0,h1,h2,h3);
      Ahl[T][m] = mk8(l0,l1,l2,l3);
    }
  }
  // b_hh n-rows (scaled) in the C operand of the NH tile
  f32x16 BHN;
#pragma unroll
  for (int r=0; r<16; r++){
    int row = (r&3) + 8*(r>>2) + 4*hb;
    BHN[r] = b_hh[2*HH + row] * 2.88539008f;
  }
  const f32x16 Z16 = {0.f,0.f,0.f,0.f,0.f,0.f,0.f,0.f,0.f,0.f,0.f,0.f,0.f,0.f,0.f,0.f};

  float h[16];
#pragma unroll
  for (int r=0;r<16;r++) h[r]=0.f;
  short8 Bh1 = mk8(0,0,0,0), Bh2 = mk8(0,0,0,0);

  // ---- staging: 32 nodes x 48 floats per chunk = 6 float4 per lane ----
  float4 ld[6];
#define PREFETCH(C) { \
  _Pragma("unroll") \
  for (int q=0;q<6;q++){ \
    int id=q*64+lane, a2=id/12, off=id%12; \
    int na=n0+a2; if (na>NN-1) na=NN-1; \
    ld[q] = *(const float4*)(price + (size_t)na*(TT*INF) + (C)*48 + off*4); \
  } }
#define STAGE(BUF) { \
  _Pragma("unroll") \
  for (int q=0;q<6;q++){ \
    int id=q*64+lane, a2=id/12, off=id%12; \
    int swz=(a2&7)<<2; unsigned* row=(BUF)+a2*64; \
    _Pragma("unroll") \
    for (int p=0;p<2;p++){ \
      float e0 = p? ld[q].z : ld[q].x; \
      float e1 = p? ld[q].w : ld[q].y; \
      int b = off*4 + p*2; int ttl = b/6; int ii = b - ttl*6; \
      unsigned hi_, lo_; pkhl(e0, e1, hi_, lo_); \
      row[(ttl*8 + (ii>>1)) ^ swz]     = hi_; \
      row[(ttl*8 + 3 + (ii>>1)) ^ swz] = lo_; \
    } } }

  PREFETCH(0); STAGE(&xs[0][0]);

  const int roff = (hb<<2) ^ ((a&7)<<2);

#pragma unroll 1
  for (int c=0;c<16;c++){
    if (c<15) PREFETCH(c+1);
    const unsigned* cell = &xs[c&1][a*64];
    unsigned* sb = &xs[(c&1)^1][0];
#pragma unroll 1
    for (int tt=0; tt<8; tt++){
      union{uint4 u; short8 s;} cv;
      cv.u = *(const uint4*)(cell + ((tt*8) ^ roff));
      // x-path: ONE mfma per tile (xh*Wh + xl*Wh + bias)
      f32x16 aR  = MFMA32(AxA[0], cv.s, Z16, 0,0,0);
      f32x16 aZ  = MFMA32(AxA[1], cv.s, Z16, 0,0,0);
      f32x16 aNX = MFMA32(AxA[2], cv.s, Z16, 0,0,0);
      f32x16 aNH = MFMA32(Ahh[2][0], Bh1, BHN, 0,0,0);
      // h-path: 2 terms x 2 K-chains
      aR = MFMA32(Ahh[0][0], Bh1, aR, 0,0,0); aR = MFMA32(Ahh[0][1], Bh2, aR, 0,0,0);
      aR = MFMA32(Ahl[0][0], Bh1, aR, 0,0,0); aR = MFMA32(Ahl[0][1], Bh2, aR, 0,0,0);
      aZ = MFMA32(Ahh[1][0], Bh1, aZ, 0,0,0); aZ = MFMA32(Ahh[1][1], Bh2, aZ, 0,0,0);
      aZ = MFMA32(Ahl[1][0], Bh1, aZ, 0,0,0); aZ = MFMA32(Ahl[1][1], Bh2, aZ, 0,0,0);
      aNH= MFMA32(Ahh[2][1], Bh2, aNH,0,0,0);
      aNH= MFMA32(Ahl[2][0], Bh1, aNH,0,0,0); aNH= MFMA32(Ahl[2][1], Bh2, aNH,0,0,0);
      // gates
#define GUPD(hvar, AR, AZ, ANX, ANH) { \
      float er = __builtin_amdgcn_exp2f(AR); \
      float rr = __builtin_amdgcn_rcpf(1.f + er); \
      float p  = (ANX) + rr*(ANH); \
      float ez = __builtin_amdgcn_exp2f(AZ); \
      float et = __builtin_amdgcn_exp2f(p); \
      float etp = et + 1.f, etm = et - 1.f; \
      float num = hvar*etp + ez*etm; \
      float den = (1.f + ez) * etp; \
      hvar = num * __builtin_amdgcn_rcpf(den); }
#pragma unroll
      for (int r=0;r<16;r++) GUPD(h[r], aR[r], aZ[r], aNX[r], aNH[r]);
      // D -> next-step B: pack pairs, half-exchange lane<->lane+32
      unsigned c0=pk2(h[0],h[1]),  c1=pk2(h[2],h[3]),  c2=pk2(h[4],h[5]),  c3=pk2(h[6],h[7]);
      unsigned c4=pk2(h[8],h[9]),  c5=pk2(h[10],h[11]), c6=pk2(h[12],h[13]), c7=pk2(h[14],h[15]);
      unsigned p0=__shfl_xor(c0,32,64), p1=__shfl_xor(c1,32,64);
      unsigned p2=__shfl_xor(c2,32,64), p3=__shfl_xor(c3,32,64);
      unsigned p4=__shfl_xor(c4,32,64), p5=__shfl_xor(c5,32,64);
      unsigned p6=__shfl_xor(c6,32,64), p7=__shfl_xor(c7,32,64);
      unsigned v0 = hb? p2 : c0, v1 = hb? p3 : c1, v2 = hb? c2 : p0, v3 = hb? c3 : p1;
      unsigned w0 = hb? p6 : c4, w1 = hb? p7 : c5, w2 = hb? c6 : p4, w3 = hb? c7 : p5;
      Bh1 = mk8(v0,v1,v2,v3);
      Bh2 = mk8(w0,w1,w2,w3);
    }
    if (c<15) STAGE(sb);
  }

  // ---- epilogue: lrelu(h), then xw = lrelu(h) @ W1^T (one 32x32 tile, 3-term) ----
  float* ldsF = (float*)&xs[0][0];   // reuse staging LDS; pad-33 transpose buffer
#pragma unroll
  for (int r=0;r<16;r++){
    int row = (r&3) + 8*(r>>2) + 4*hb;
    ldsF[a*33 + row] = lrelu(h[r], 0.01f);
  }
  // build B fragments of lrelu(h): lane (col=a) reads rows k = m*16 + hb*8 + e
  float b1v[8], b2v[8];
#pragma unroll
  for (int e=0;e<8;e++){
    b1v[e] = ldsF[a*33 + hb*8 + e];
    b2v[e] = ldsF[a*33 + 16 + hb*8 + e];
  }
  unsigned q0,s0,q1,s1,q2,s2,q3,s3;
  pkhl(b1v[0],b1v[1],q0,s0); pkhl(b1v[2],b1v[3],q1,s1);
  pkhl(b1v[4],b1v[5],q2,s2); pkhl(b1v[6],b1v[7],q3,s3);
  short8 Brh1 = mk8(q0,q1,q2,q3), Brl1 = mk8(s0,s1,s2,s3);
  pkhl(b2v[0],b2v[1],q0,s0); pkhl(b2v[2],b2v[3],q1,s1);
  pkhl(b2v[4],b2v[5],q2,s2); pkhl(b2v[6],b2v[7],q3,s3);
  short8 Brh2 = mk8(q0,q1,q2,q3), Brl2 = mk8(s0,s1,s2,s3);
  // W1 A fragments (feature = a), 2 K-chains, hi/lo
  short8 W1h[2], W1l[2];
#pragma unroll
  for (int m=0;m<2;m++){
    const float* wp = W1 + a*HH + m*16 + hb*8;
    float4 wa = *(const float4*)(wp);
    float4 wb = *(const float4*)(wp+4);
    unsigned h0,l0,h1,l1,h2,l2,h3,l3;
    pkhl(wa.x,wa.y,h0,l0); pkhl(wa.z,wa.w,h1,l1);
    pkhl(wb.x,wb.y,h2,l2); pkhl(wb.z,wb.w,h3,l3);
    W1h[m] = mk8(h0,h1,h2,h3);
    W1l[m] = mk8(l0,l1,l2,l3);
  }
  f32x16 o = MFMA32(W1h[0], Brh1, Z16, 0,0,0);
  o = MFMA32(W1h[1], Brh2, o, 0,0,0);
  o = MFMA32(W1h[0], Brl1, o, 0,0,0);
  o = MFMA32(W1h[1], Brl2, o, 0,0,0);
  o = MFMA32(W1l[0], Brh1, o, 0,0,0);
  o = MFMA32(W1l[1], Brh2, o, 0,0,0);
  // transpose via LDS (overwrites the rh buffer; same wave, ordered) and store coalesced
#pragma unroll
  for (int r=0;r<16;r++){
    int row = (r&3) + 8*(r>>2) + 4*hb;
    ldsF[a*33 + row] = o[r];
  }
  {
    int nn = lane>>1, f0 = (lane&1)*16;
    if (n0 + nn < NN){
#pragma unroll
      for (int q=0;q<4;q++){
        float4 v;
        v.x = ldsF[nn*33 + f0 + q*4 + 0];
        v.y = ldsF[nn*33 + f0 + q*4 + 1];
        v.z = ldsF[nn*33 + f0 + q*4 + 2];
        v.w = ldsF[nn*33 + f0 + q*4 + 3];
        *(float4*)(xw + (size_t)(n0+nn)*HH + f0 + q*4) = v;
      }
    }
  }
}

// ============== edge-CSR build (once, reused by both convs) ==============
// counts per edge into ecur; node degrees (float) into degD
__global__ __launch_bounds__(256) void csr_count(const int* __restrict__ eidx, const int* __restrict__ nidx,
                                                 int* __restrict__ ecnt, float* __restrict__ degD){
  int i = blockIdx.x*256 + threadIdx.x;
  if (i < NI){
    atomicAdd(&ecnt[eidx[i]], 1);
    atomicAdd(&degD[nidx[i]], 1.f);
  }
}

// single-block PARALLEL exclusive scan over 2000 edge counts (8/thread,
// shfl wave scan + 4-entry wave-total pass); writes eoff and resets
// ecur to running offsets (fill cursors).
__global__ __launch_bounds__(256) void escan(int* __restrict__ ecur, int* __restrict__ eoff){
  __shared__ int wt[4];
  int tid = threadIdx.x, lane = tid & 63, wv = tid >> 6;
  int base = tid*8;
  int c[8]; int s = 0;
#pragma unroll
  for (int k=0;k<8;k++){ int i=base+k; c[k] = (i<NE) ? ecur[i] : 0; s += c[k]; }
  int inc = s;
#pragma unroll
  for (int o=1;o<64;o<<=1){ int v=__shfl_up(inc,o,64); if (lane>=o) inc += v; }
  if (lane==63) wt[wv] = inc;
  __syncthreads();
  if (tid==0){ int r=0; for (int t=0;t<4;t++){ int v=wt[t]; wt[t]=r; r+=v; } }
  __syncthreads();
  int run = wt[wv] + inc - s;
#pragma unroll
  for (int k=0;k<8;k++){ int i=base+k; if (i<NE){ eoff[i]=run; ecur[i]=run; run += c[k]; } }
  if (tid==0) eoff[NE] = NI;
}

__global__ __launch_bounds__(256) void csr_fill(const int* __restrict__ nidx, const int* __restrict__ eidx,
                                                int* __restrict__ ecur, int* __restrict__ elist){
  int i = blockIdx.x*256 + threadIdx.x;
  if (i < NI){
    int se = atomicAdd(&ecur[eidx[i]], 1);
    elist[se] = nidx[i];               // edge -> node ids
  }
}

// ====== edge gather: zero atomics. one 256-thread block per edge ======
// eacc[e] = (1/B_e) * sum_{incident nodes} xw[node]   (Binv folded in)
__global__ __launch_bounds__(256) void egather(const float* __restrict__ xw, const int* __restrict__ elist,
                                               const int* __restrict__ eoff, float* __restrict__ eacc){
  __shared__ float red[8][HH];
  int e = blockIdx.x;
  int tid = threadIdx.x;
  int f = tid & 31, grp = tid >> 5;          // 8 j-streams
  int o0 = eoff[e], o1 = eoff[e+1];
  float acc = 0.f;
  for (int j = o0 + grp; j < o1; j += 8)
    acc += xw[(size_t)elist[j]*HH + f];
  red[grp][f] = acc;
  __syncthreads();
  if (tid < 32){
    float s = red[0][f]+red[1][f]+red[2][f]+red[3][f]
            + red[4][f]+red[5][f]+red[6][f]+red[7][f];
    int d = o1 - o0;
    float bi = d > 0 ? 1.f/(float)d : 0.f;
    eacc[(size_t)e*HH + f] = s*bi;
  }
}

// ---------------- node scatter: nacc += eacc[e] per incidence (mean already folded) ----------------
__global__ __launch_bounds__(256) void scat_n(const float* __restrict__ eacc,
                                              const int* __restrict__ nidx, const int* __restrict__ eidx,
                                              float* __restrict__ nacc){
  int idx = blockIdx.x*256 + threadIdx.x;   // NI*32 exact
  int i = idx >> 5, f = idx & 31;
  int nd = nidx[i], e = eidx[i];
  atomicAdd(&nacc[(size_t)nd*HH + f], eacc[(size_t)e*HH + f]);
}

// ---------------- x1 = leaky(nacc*Dinv + b, .2); Y = x1 @ W^T; nacc:=0 ----------------
__global__ __launch_bounds__(256) void finmm(float* __restrict__ nacc, const float* __restrict__ degD,
                                             const float* __restrict__ bias, const float* __restrict__ W,
                                             float* __restrict__ Y){
  __shared__ float sWt[HH*HH];
  __shared__ float sX[8*HH];
  int tid = threadIdx.x;
  int f0 = tid>>5, k = tid&31;
#pragma unroll
  for (int q=0;q<4;q++) sWt[k*HH + (q*8+f0)] = W[(q*8+f0)*HH + k];
  size_t base = (size_t)blockIdx.x*8*HH;
  int n = blockIdx.x*8 + (tid>>5);
  float d = degD[n];
  float dinv = d > 0.f ? 1.f/d : 0.f;
  sX[tid] = lrelu(nacc[base + tid]*dinv + bias[tid&31], 0.2f);
  nacc[base + tid] = 0.f;   // reset for conv2
  __syncthreads();
  float a = 0.f;
#pragma unroll
  for (int kk=0;kk<HH;kk++) a += sX[(tid>>5)*HH+kk]*sWt[kk*HH+(tid&31)];
  Y[base + tid] = a;
}

// ---------------- x2 = leaky(nacc*Dinv + b2, .2); out = leaky(x2@Wl^T + bl, .01) ----------------
__global__ __launch_bounds__(256) void fin_final(const float* __restrict__ nacc, const float* __restrict__ degD,
                                                 const float* __restrict__ b2, const float* __restrict__ Wl,
                                                 const float* __restrict__ bl, float* __restrict__ out){
  __shared__ float sWl[HH*RR];
  __shared__ float sX[8*HH];
  int tid = threadIdx.x;
#pragma unroll
  for (int q=0;q<2;q++){
    int idx = q*256 + tid;        // 512 = RR*HH
    int r = idx >> 5, kk = idx & 31;
    sWl[kk*RR + r] = Wl[idx];
  }
  size_t base = (size_t)blockIdx.x*8*HH;
  int n = blockIdx.x*8 + (tid>>5);
  float d = degD[n];
  float dinv = d > 0.f ? 1.f/d : 0.f;
  sX[tid] = lrelu(nacc[base + tid]*dinv + b2[tid&31], 0.2f);
  __syncthreads();
  int ln = tid>>5, r = tid&31;
  if (r < RR){
    float a = bl[r];
#pragma unroll
    for (int kk=0;kk<HH;kk++) a += sX[ln*HH+kk]*sWl[kk*RR+r];
    out[(size_t)(blockIdx.x*8+ln)*RR + r] = lrelu(a, 0.01f);
  }
}

// d_out slack layout (800000 float slots; fin_final rewrites all of out
// at the very end):
//   eacc  f32[64000]  @ 0
//   eoff  i32[2001]   @ 64000
//   ecur  i32[2000]   @ 66001   (counts, then fill cursors)
//   elist i32[150000] @ 68001   (node ids per edge)
//   end 218001 < 800000
#define O_EACC  0
#define O_EOFF  64000
#define O_ECUR  66001
#define O_ELIST 68001

extern "C" void kernel_launch(void* const* d_in, const int* in_sizes, int n_in,
                              void* d_out, int out_size, void* d_ws, size_t ws_size,
                              hipStream_t stream){
  const float* price = (const float*)d_in[0];
  // d_in[1] = concept: unused (PreAttn path disabled in reference)
  const float* W_ih = (const float*)d_in[2];
  const float* W_hh = (const float*)d_in[3];
  const float* b_ih = (const float*)d_in[4];
  const float* b_hh = (const float*)d_in[5];
  const float* W1   = (const float*)d_in[6];
  const float* b1   = (const float*)d_in[7];
  const float* W2   = (const float*)d_in[8];
  const float* b2   = (const float*)d_in[9];
  const float* Wl   = (const float*)d_in[10];
  const float* bl   = (const float*)d_in[11];
  const int* nidx   = (const int*)d_in[12];
  const int* eidx   = (const int*)d_in[13];
  float* out = (float*)d_out;
  int*  outI = (int*)d_out;

  // ws layout (proven size): xw | nacc | degD
  float* ws   = (float*)d_ws;
  float* xw   = ws;                 // N*32
  float* nacc = ws + 1600000;       // N*32
  float* degD = ws + 3200000;       // 50000

  // d_out slack (dead until fin_final rewrites everything)
  float* eacc = out  + O_EACC;
  int* eoff   = outI + O_EOFF;
  int* ecur   = outI + O_ECUR;
  int* elist  = outI + O_ELIST;

  // zero nacc+degD (contiguous) and the edge counters
  hipMemsetAsync(nacc, 0, (1600000+50000)*sizeof(float), stream);
  hipMemsetAsync(ecur, 0, NE*sizeof(int), stream);

  // edge-CSR build (independent of GRU output; degD counted here)
  csr_count<<<586, 256, 0, stream>>>(eidx, nidx, ecur, degD);
  escan<<<1, 256, 0, stream>>>(ecur, eoff);
  csr_fill<<<586, 256, 0, stream>>>(nidx, eidx, ecur, elist);

  gru_mfma<<<1563, 64, 0, stream>>>(price, W_ih, W_hh, b_ih, b_hh, W1, xw, eacc);

  // conv1: edge side gather (zero atomics), node side proven atomic scatter
  egather<<<NE, 256, 0, stream>>>(xw, elist, eoff, eacc);
  scat_n<<<18750, 256, 0, stream>>>(eacc, nidx, eidx, nacc);
  finmm<<<6250, 256, 0, stream>>>(nacc, degD, b1, W2, xw);   // x1 -> @W2 -> xw; nacc := 0

  // conv2
  egather<<<NE, 256, 0, stream>>>(xw, elist, eoff, eacc);
  scat_n<<<18750, 256, 0, stream>>>(eacc, nidx, eidx, nacc);
  fin_final<<<6250, 256, 0, stream>>>(nacc, degD, b2, Wl, bl, out);
}

// Round 8
// 347.530 us; speedup vs baseline: 1.4796x; 1.0178x over previous
//
#include <hip/hip_runtime.h>
#include <hip/hip_bf16.h>
#include <cstdint>

#define NN 50000
#define TT 128
#define INF 6
#define HH 32
#define NE 2000
#define NI 150000
#define RR 16

typedef __attribute__((ext_vector_type(4)))  float f32x4;
typedef __attribute__((ext_vector_type(16))) float f32x16;
typedef __attribute__((ext_vector_type(8)))  short short8;

__device__ __forceinline__ float lrelu(float x, float s){ return x > 0.f ? x : s*x; }

// ---- packed bf16 helpers (v_cvt_pk_bf16_f32 path) ----
__device__ __forceinline__ unsigned pk2(float a, float b){        // [bf16(a) | bf16(b)<<16]
  union { __hip_bfloat162 h; unsigned u; } t;
  t.h = __float22bfloat162_rn(make_float2(a, b));
  return t.u;
}
__device__ __forceinline__ void pkhl(float a, float b, unsigned &hi, unsigned &lo){
  hi = pk2(a, b);
  float ha = __uint_as_float(hi << 16);
  float hb = __uint_as_float(hi & 0xFFFF0000u);
  lo = pk2(a - ha, b - hb);
}
__device__ __forceinline__ unsigned pksplit(float x){             // (hi(x), lo(x)) in one u32
  unsigned h = pk2(x, 0.f) & 0xFFFFu;
  float hf = __uint_as_float(h << 16);
  unsigned l = pk2(x - hf, 0.f) & 0xFFFFu;
  return h | (l << 16);
}
__device__ __forceinline__ short8 mk8(unsigned a, unsigned b, unsigned c, unsigned d){
  union { unsigned u[4]; short8 v; } t;
  t.u[0]=a; t.u[1]=b; t.u[2]=c; t.u[3]=d;
  return t.v;
}
#define MFMA32 __builtin_amdgcn_mfma_f32_32x32x16_bf16

// =====================================================================
// SESSION-FINAL: exact R0 configuration (best measured: 347.1us).
// GRU on mfma_f32_32x32x16_bf16. One wave = 32 nodes (D cols). Gate
// tiles: T0=r rows, T1=z, T2=n. x-path is ONE mfma per tile; h-path =
// 2 terms x 2 K-chains. 15 MFMA / 32 nodes / step. D(reg r)->row
// (r&3)+8*(r>>2)+4*hb; next-step B built with 8 shfl_xor(32)+selects.
// exp2 folded into weights; 5-trans GUPD; unroll 1.
// Evidence ledger (R0-R7):
//  - GRU 233us invariant across: 16x16 tiles/3125 waves (R1), 4-wave
//    WGs (R3), 2-tile ILP (R6: VGPR 192, 294us), reg caps (R2: spills).
//    VALUBusy 52-57% trans-dominated; recurrence serializes the rest.
//  - Conv 114us floor: atomic scatter beats e-CSR hybrid (120us, R7)
//    and full CSR gather (212us, R5). Index-stream + small-kernel
//    latency bound, not atomic contention.
// =====================================================================
__global__ __launch_bounds__(64,2) void gru_mfma(
    const float* __restrict__ price,
    const float* __restrict__ W_ih, const float* __restrict__ W_hh,
    const float* __restrict__ b_ih, const float* __restrict__ b_hh,
    const float* __restrict__ W1,
    float* __restrict__ xw, float* __restrict__ eaccZ)
{
  __shared__ __align__(16) unsigned xs[2][2048];   // [buf][32 nodes * 64 u32] = 16 KB

  const int lane = threadIdx.x;
  const int a    = lane & 31;    // node col
  const int hb   = lane >> 5;    // half: 0=lo, 1=hi
  const int n0   = blockIdx.x*32;   // 1563 blocks; last block 16 valid nodes

  // fold eacc zeroing into this launch (runs before scat_e kernel)
  { int gt = blockIdx.x*64 + lane; if (gt < NE*HH) eaccZ[gt] = 0.f; }

  // const slots P6=(1,1)bf16, P7=0 per cell, both buffers
  for (int idx = lane; idx < 512; idx += 64){
    int bsel = idx >> 8, rem = idx & 255;
    int nd = rem >> 3, t7 = rem & 7;
    int swz = (nd&7)<<2;
    xs[bsel][nd*64 + ((t7*8+6) ^ swz)] = 0x3F803F80u;
    xs[bsel][nd*64 + ((t7*8+7) ^ swz)] = 0u;
  }

  // ---- A fragments ----
  short8 AxA[3], Ahh[3][2], Ahl[3][2];   // [tile][K-chain]
#pragma unroll
  for (int T=0; T<3; T++){
    const int gr = T*32 + a;             // gate row: r=0-31, z=32-63, n=64-95
    const float sc = (T<2) ? -1.44269504f : 2.88539008f;
    // x-path A: lo lanes k0-7 = {W0..W5, W0,W1}; hi k8-15 = {W2..W5, bh,bl, 0,0}
    const float* vi = W_ih + gr*INF;
    const float w0=vi[0]*sc, w1=vi[1]*sc, w2=vi[2]*sc, w3=vi[3]*sc, w4=vi[4]*sc, w5=vi[5]*sc;
    const float bias = (b_ih[gr] + ((T<2) ? b_hh[gr] : 0.f)) * sc;
    if (hb==0) AxA[T] = mk8(pk2(w0,w1), pk2(w2,w3), pk2(w4,w5), pk2(w0,w1));
    else       AxA[T] = mk8(pk2(w2,w3), pk2(w4,w5), pksplit(bias), 0u);
    // h-path A (double-bf16 weights), chain m covers k=16m..16m+15
#pragma unroll
    for (int m=0; m<2; m++){
      const float* wp = W_hh + gr*HH + m*16 + hb*8;
      float4 wa = *(const float4*)(wp);
      float4 wb = *(const float4*)(wp+4);
      wa.x*=sc; wa.y*=sc; wa.z*=sc; wa.w*=sc;
      wb.x*=sc; wb.y*=sc; wb.z*=sc; wb.w*=sc;
      unsigned h0,l0,h1,l1,h2,l2,h3,l3;
      pkhl(wa.x,wa.y,h0,l0); pkhl(wa.z,wa.w,h1,l1);
      pkhl(wb.x,wb.y,h2,l2); pkhl(wb.z,wb.w,h3,l3);
      Ahh[T][m] = mk8(h0,h1,h2,h3);
      Ahl[T][m] = mk8(l0,l1,l2,l3);
    }
  }
  // b_hh n-rows (scaled) in the C operand of the NH tile
  f32x16 BHN;
#pragma unroll
  for (int r=0; r<16; r++){
    int row = (r&3) + 8*(r>>2) + 4*hb;
    BHN[r] = b_hh[2*HH + row] * 2.88539008f;
  }
  const f32x16 Z16 = {0.f,0.f,0.f,0.f,0.f,0.f,0.f,0.f,0.f,0.f,0.f,0.f,0.f,0.f,0.f,0.f};

  float h[16];
#pragma unroll
  for (int r=0;r<16;r++) h[r]=0.f;
  short8 Bh1 = mk8(0,0,0,0), Bh2 = mk8(0,0,0,0);

  // ---- staging: 32 nodes x 48 floats per chunk = 6 float4 per lane ----
  float4 ld[6];
#define PREFETCH(C) { \
  _Pragma("unroll") \
  for (int q=0;q<6;q++){ \
    int id=q*64+lane, a2=id/12, off=id%12; \
    int na=n0+a2; if (na>NN-1) na=NN-1; \
    ld[q] = *(const float4*)(price + (size_t)na*(TT*INF) + (C)*48 + off*4); \
  } }
#define STAGE(BUF) { \
  _Pragma("unroll") \
  for (int q=0;q<6;q++){ \
    int id=q*64+lane, a2=id/12, off=id%12; \
    int swz=(a2&7)<<2; unsigned* row=(BUF)+a2*64; \
    _Pragma("unroll") \
    for (int p=0;p<2;p++){ \
      float e0 = p? ld[q].z : ld[q].x; \
      float e1 = p? ld[q].w : ld[q].y; \
      int b = off*4 + p*2; int ttl = b/6; int ii = b - ttl*6; \
      unsigned hi_, lo_; pkhl(e0, e1, hi_, lo_); \
      row[(ttl*8 + (ii>>1)) ^ swz]     = hi_; \
      row[(ttl*8 + 3 + (ii>>1)) ^ swz] = lo_; \
    } } }

  PREFETCH(0); STAGE(&xs[0][0]);

  const int roff = (hb<<2) ^ ((a&7)<<2);

#pragma unroll 1
  for (int c=0;c<16;c++){
    if (c<15) PREFETCH(c+1);
    const unsigned* cell = &xs[c&1][a*64];
    unsigned* sb = &xs[(c&1)^1][0];
#pragma unroll 1
    for (int tt=0; tt<8; tt++){
      union{uint4 u; short8 s;} cv;
      cv.u = *(const uint4*)(cell + ((tt*8) ^ roff));
      // x-path: ONE mfma per tile (xh*Wh + xl*Wh + bias)
      f32x16 aR  = MFMA32(AxA[0], cv.s, Z16, 0,0,0);
      f32x16 aZ  = MFMA32(AxA[1], cv.s, Z16, 0,0,0);
      f32x16 aNX = MFMA32(AxA[2], cv.s, Z16, 0,0,0);
      f32x16 aNH = MFMA32(Ahh[2][0], Bh1, BHN, 0,0,0);
      // h-path: 2 terms x 2 K-chains
      aR = MFMA32(Ahh[0][0], Bh1, aR, 0,0,0); aR = MFMA32(Ahh[0][1], Bh2, aR, 0,0,0);
      aR = MFMA32(Ahl[0][0], Bh1, aR, 0,0,0); aR = MFMA32(Ahl[0][1], Bh2, aR, 0,0,0);
      aZ = MFMA32(Ahh[1][0], Bh1, aZ, 0,0,0); aZ = MFMA32(Ahh[1][1], Bh2, aZ, 0,0,0);
      aZ = MFMA32(Ahl[1][0], Bh1, aZ, 0,0,0); aZ = MFMA32(Ahl[1][1], Bh2, aZ, 0,0,0);
      aNH= MFMA32(Ahh[2][1], Bh2, aNH,0,0,0);
      aNH= MFMA32(Ahl[2][0], Bh1, aNH,0,0,0); aNH= MFMA32(Ahl[2][1], Bh2, aNH,0,0,0);
      // gates
#define GUPD(hvar, AR, AZ, ANX, ANH) { \
      float er = __builtin_amdgcn_exp2f(AR); \
      float rr = __builtin_amdgcn_rcpf(1.f + er); \
      float p  = (ANX) + rr*(ANH); \
      float ez = __builtin_amdgcn_exp2f(AZ); \
      float et = __builtin_amdgcn_exp2f(p); \
      float etp = et + 1.f, etm = et - 1.f; \
      float num = hvar*etp + ez*etm; \
      float den = (1.f + ez) * etp; \
      hvar = num * __builtin_amdgcn_rcpf(den); }
#pragma unroll
      for (int r=0;r<16;r++) GUPD(h[r], aR[r], aZ[r], aNX[r], aNH[r]);
      // D -> next-step B: pack pairs, half-exchange lane<->lane+32
      unsigned c0=pk2(h[0],h[1]),  c1=pk2(h[2],h[3]),  c2=pk2(h[4],h[5]),  c3=pk2(h[6],h[7]);
      unsigned c4=pk2(h[8],h[9]),  c5=pk2(h[10],h[11]), c6=pk2(h[12],h[13]), c7=pk2(h[14],h[15]);
      unsigned p0=__shfl_xor(c0,32,64), p1=__shfl_xor(c1,32,64);
      unsigned p2=__shfl_xor(c2,32,64), p3=__shfl_xor(c3,32,64);
      unsigned p4=__shfl_xor(c4,32,64), p5=__shfl_xor(c5,32,64);
      unsigned p6=__shfl_xor(c6,32,64), p7=__shfl_xor(c7,32,64);
      unsigned v0 = hb? p2 : c0, v1 = hb? p3 : c1, v2 = hb? c2 : p0, v3 = hb? c3 : p1;
      unsigned w0 = hb? p6 : c4, w1 = hb? p7 : c5, w2 = hb? c6 : p4, w3 = hb? c7 : p5;
      Bh1 = mk8(v0,v1,v2,v3);
      Bh2 = mk8(w0,w1,w2,w3);
    }
    if (c<15) STAGE(sb);
  }

  // ---- epilogue: lrelu(h), then xw = lrelu(h) @ W1^T (one 32x32 tile, 3-term) ----
  float* ldsF = (float*)&xs[0][0];   // reuse staging LDS; pad-33 transpose buffer
#pragma unroll
  for (int r=0;r<16;r++){
    int row = (r&3) + 8*(r>>2) + 4*hb;
    ldsF[a*33 + row] = lrelu(h[r], 0.01f);
  }
  // build B fragments of lrelu(h): lane (col=a) reads rows k = m*16 + hb*8 + e
  float b1v[8], b2v[8];
#pragma unroll
  for (int e=0;e<8;e++){
    b1v[e] = ldsF[a*33 + hb*8 + e];
    b2v[e] = ldsF[a*33 + 16 + hb*8 + e];
  }
  unsigned q0,s0,q1,s1,q2,s2,q3,s3;
  pkhl(b1v[0],b1v[1],q0,s0); pkhl(b1v[2],b1v[3],q1,s1);
  pkhl(b1v[4],b1v[5],q2,s2); pkhl(b1v[6],b1v[7],q3,s3);
  short8 Brh1 = mk8(q0,q1,q2,q3), Brl1 = mk8(s0,s1,s2,s3);
  pkhl(b2v[0],b2v[1],q0,s0); pkhl(b2v[2],b2v[3],q1,s1);
  pkhl(b2v[4],b2v[5],q2,s2); pkhl(b2v[6],b2v[7],q3,s3);
  short8 Brh2 = mk8(q0,q1,q2,q3), Brl2 = mk8(s0,s1,s2,s3);
  // W1 A fragments (feature = a), 2 K-chains, hi/lo
  short8 W1h[2], W1l[2];
#pragma unroll
  for (int m=0;m<2;m++){
    const float* wp = W1 + a*HH + m*16 + hb*8;
    float4 wa = *(const float4*)(wp);
    float4 wb = *(const float4*)(wp+4);
    unsigned h0,l0,h1,l1,h2,l2,h3,l3;
    pkhl(wa.x,wa.y,h0,l0); pkhl(wa.z,wa.w,h1,l1);
    pkhl(wb.x,wb.y,h2,l2); pkhl(wb.z,wb.w,h3,l3);
    W1h[m] = mk8(h0,h1,h2,h3);
    W1l[m] = mk8(l0,l1,l2,l3);
  }
  f32x16 o = MFMA32(W1h[0], Brh1, Z16, 0,0,0);
  o = MFMA32(W1h[1], Brh2, o, 0,0,0);
  o = MFMA32(W1h[0], Brl1, o, 0,0,0);
  o = MFMA32(W1h[1], Brl2, o, 0,0,0);
  o = MFMA32(W1l[0], Brh1, o, 0,0,0);
  o = MFMA32(W1l[1], Brh2, o, 0,0,0);
  // transpose via LDS (overwrites the rh buffer; same wave, ordered) and store coalesced
#pragma unroll
  for (int r=0;r<16;r++){
    int row = (r&3) + 8*(r>>2) + 4*hb;
    ldsF[a*33 + row] = o[r];
  }
  {
    int nn = lane>>1, f0 = (lane&1)*16;
    if (n0 + nn < NN){
#pragma unroll
      for (int q=0;q<4;q++){
        float4 v;
        v.x = ldsF[nn*33 + f0 + q*4 + 0];
        v.y = ldsF[nn*33 + f0 + q*4 + 1];
        v.z = ldsF[nn*33 + f0 + q*4 + 2];
        v.w = ldsF[nn*33 + f0 + q*4 + 3];
        *(float4*)(xw + (size_t)(n0+nn)*HH + f0 + q*4) = v;
      }
    }
  }
}

// ---------------- scatter xw -> edge accumulators (+degree count on 1st pass) ----------------
template<bool COUNT>
__global__ __launch_bounds__(256) void scat_e(const float* __restrict__ xw, const int* __restrict__ nidx,
                                              const int* __restrict__ eidx, float* __restrict__ eacc,
                                              float* __restrict__ degD, float* __restrict__ degB){
  int idx = blockIdx.x*256 + threadIdx.x;   // NI*32 exact
  int i = idx >> 5, f = idx & 31;
  int nd = nidx[i], e = eidx[i];
  if (COUNT && f == 0){
    atomicAdd(&degD[nd], 1.f);
    atomicAdd(&degB[e], 1.f);
  }
  atomicAdd(&eacc[(size_t)e*HH + f], xw[(size_t)nd*HH + f]);
}
template __global__ void scat_e<true>(const float*, const int*, const int*, float*, float*, float*);
template __global__ void scat_e<false>(const float*, const int*, const int*, float*, float*, float*);

// ---------------- gather edge means -> node accumulators ----------------
__global__ __launch_bounds__(256) void scat_n(const float* __restrict__ eacc, const float* __restrict__ degB,
                                              const int* __restrict__ nidx, const int* __restrict__ eidx,
                                              float* __restrict__ nacc){
  int idx = blockIdx.x*256 + threadIdx.x;   // NI*32 exact
  int i = idx >> 5, f = idx & 31;
  int nd = nidx[i], e = eidx[i];
  float b = degB[e];
  float binv = b > 0.f ? 1.f/b : 0.f;
  atomicAdd(&nacc[(size_t)nd*HH + f], eacc[(size_t)e*HH + f]*binv);
}

// ---------------- x1 = leaky(nacc*Dinv + b, .2); Y = x1 @ W^T; nacc:=0; eacc:=0 ----------------
__global__ __launch_bounds__(256) void finmm(float* __restrict__ nacc, const float* __restrict__ degD,
                                             const float* __restrict__ bias, const float* __restrict__ W,
                                             float* __restrict__ Y, float* __restrict__ eacc){
  __shared__ float sWt[HH*HH];
  __shared__ float sX[8*HH];
  int tid = threadIdx.x;
  if (blockIdx.x < 250) eacc[blockIdx.x*256 + tid] = 0.f;   // re-zero for conv2 (250*256 = 64000)
  int f0 = tid>>5, k = tid&31;
#pragma unroll
  for (int q=0;q<4;q++) sWt[k*HH + (q*8+f0)] = W[(q*8+f0)*HH + k];
  size_t base = (size_t)blockIdx.x*8*HH;
  int n = blockIdx.x*8 + (tid>>5);
  float d = degD[n];
  float dinv = d > 0.f ? 1.f/d : 0.f;
  sX[tid] = lrelu(nacc[base + tid]*dinv + bias[tid&31], 0.2f);
  nacc[base + tid] = 0.f;   // reset for conv2
  __syncthreads();
  float a = 0.f;
#pragma unroll
  for (int kk=0;kk<HH;kk++) a += sX[(tid>>5)*HH+kk]*sWt[kk*HH+(tid&31)];
  Y[base + tid] = a;
}

// ---------------- x2 = leaky(nacc*Dinv + b2, .2); out = leaky(x2@Wl^T + bl, .01) ----------------
__global__ __launch_bounds__(256) void fin_final(const float* __restrict__ nacc, const float* __restrict__ degD,
                                                 const float* __restrict__ b2, const float* __restrict__ Wl,
                                                 const float* __restrict__ bl, float* __restrict__ out){
  __shared__ float sWl[HH*RR];
  __shared__ float sX[8*HH];
  int tid = threadIdx.x;
#pragma unroll
  for (int q=0;q<2;q++){
    int idx = q*256 + tid;        // 512 = RR*HH
    int r = idx >> 5, kk = idx & 31;
    sWl[kk*RR + r] = Wl[idx];
  }
  size_t base = (size_t)blockIdx.x*8*HH;
  int n = blockIdx.x*8 + (tid>>5);
  float d = degD[n];
  float dinv = d > 0.f ? 1.f/d : 0.f;
  sX[tid] = lrelu(nacc[base + tid]*dinv + b2[tid&31], 0.2f);
  __syncthreads();
  int ln = tid>>5, r = tid&31;
  if (r < RR){
    float a = bl[r];
#pragma unroll
    for (int kk=0;kk<HH;kk++) a += sX[ln*HH+kk]*sWl[kk*RR+r];
    out[(size_t)(blockIdx.x*8+ln)*RR + r] = lrelu(a, 0.01f);
  }
}

extern "C" void kernel_launch(void* const* d_in, const int* in_sizes, int n_in,
                              void* d_out, int out_size, void* d_ws, size_t ws_size,
                              hipStream_t stream){
  const float* price = (const float*)d_in[0];
  // d_in[1] = concept: unused (PreAttn path disabled in reference)
  const float* W_ih = (const float*)d_in[2];
  const float* W_hh = (const float*)d_in[3];
  const float* b_ih = (const float*)d_in[4];
  const float* b_hh = (const float*)d_in[5];
  const float* W1   = (const float*)d_in[6];
  const float* b1   = (const float*)d_in[7];
  const float* W2   = (const float*)d_in[8];
  const float* b2   = (const float*)d_in[9];
  const float* Wl   = (const float*)d_in[10];
  const float* bl   = (const float*)d_in[11];
  const int* nidx   = (const int*)d_in[12];
  const int* eidx   = (const int*)d_in[13];
  float* out = (float*)d_out;

  // ws layout (13.008 MB, proven size): xw | nacc | degD | degB
  float* ws   = (float*)d_ws;
  float* xw   = ws;                 // N*32
  float* nacc = ws + 1600000;       // N*32
  float* degD = ws + 3200000;       // 50000
  float* degB = ws + 3250000;       // 2000
  float* eacc = out;                // NE*32 = 64000 floats in d_out; dead before fin_final

  // one memset: nacc+degD+degB contiguous. eacc zeroed inside gru_mfma.
  hipMemsetAsync(nacc, 0, (1600000+52000)*sizeof(float), stream);

  gru_mfma<<<1563, 64, 0, stream>>>(price, W_ih, W_hh, b_ih, b_hh, W1, xw, eacc);

  // conv1 (xw = lrelu(hT)@W1^T fused in GRU epilogue; degrees counted in scat_e)
  scat_e<true><<<18750, 256, 0, stream>>>(xw, nidx, eidx, eacc, degD, degB);
  scat_n<<<18750, 256, 0, stream>>>(eacc, degB, nidx, eidx, nacc);
  finmm<<<6250, 256, 0, stream>>>(nacc, degD, b1, W2, xw, eacc);   // x1 -> @W2 -> xw; nacc,eacc := 0

  // conv2
  scat_e<false><<<18750, 256, 0, stream>>>(xw, nidx, eidx, eacc, degD, degB);
  scat_n<<<18750, 256, 0, stream>>>(eacc, degB, nidx, eidx, nacc);
  fin_final<<<6250, 256, 0, stream>>>(nacc, degD, b2, Wl, bl, out);
}